// Round 1
// baseline (866.041 us; speedup 1.0000x reference)
//
#include <hip/hip_runtime.h>

typedef __bf16 bf16_t;
typedef __bf16 bf16x8 __attribute__((ext_vector_type(8)));
typedef float  f32x4  __attribute__((ext_vector_type(4)));

#define MFMA16(a,b,c) __builtin_amdgcn_mfma_f32_16x16x32_bf16((a),(b),(c),0,0,0)

// ---- constants (problem is fixed-shape) ----
#define BB 8
#define NN 2048
#define CC 128
#define CIN 64
#define KNB 16            // neighbors
#define BNT (BB*NN)       // 16384 points

static __device__ __forceinline__ bf16x8 cvt8(const float* src) {
  f32x4 a0 = *(const f32x4*)src;
  f32x4 a1 = *(const f32x4*)(src + 4);
  bf16x8 fr;
  fr[0] = (__bf16)a0[0]; fr[1] = (__bf16)a0[1]; fr[2] = (__bf16)a0[2]; fr[3] = (__bf16)a0[3];
  fr[4] = (__bf16)a1[0]; fr[5] = (__bf16)a1[1]; fr[6] = (__bf16)a1[2]; fr[7] = (__bf16)a1[3];
  return fr;
}

// ============================================================
// Kernel 1: in_proj (Win @ x_col + bin) fused with LayerNorm1.
// grid = 16384 blocks (one per point), block = 128 threads (one per channel)
// ============================================================
__global__ __launch_bounds__(128) void inproj_ln_k(
    const float* __restrict__ x, const float* __restrict__ Win, const float* __restrict__ bin,
    const float* __restrict__ g1, const float* __restrict__ b1,
    float* __restrict__ h, float* __restrict__ hn) {
  int bn = blockIdx.x;
  int b = bn >> 11, n = bn & (NN - 1);
  __shared__ float xs[CIN];
  __shared__ float red[CC];
  int t = threadIdx.x;
  if (t < CIN) xs[t] = x[((size_t)b * CIN + t) * NN + n];
  __syncthreads();
  float acc = bin[t];
  const float* wr = Win + t * CIN;
  #pragma unroll
  for (int i = 0; i < CIN; i += 4) {
    f32x4 w4 = *(const f32x4*)(wr + i);
    acc += w4[0] * xs[i] + w4[1] * xs[i + 1] + w4[2] * xs[i + 2] + w4[3] * xs[i + 3];
  }
  h[(size_t)bn * CC + t] = acc;
  red[t] = acc; __syncthreads();
  for (int s = 64; s > 0; s >>= 1) { if (t < s) red[t] += red[t + s]; __syncthreads(); }
  float mu = red[0] * (1.f / CC);
  __syncthreads();
  float d = acc - mu;
  red[t] = d * d; __syncthreads();
  for (int s = 64; s > 0; s >>= 1) { if (t < s) red[t] += red[t + s]; __syncthreads(); }
  float var = red[0] * (1.f / CC);
  hn[(size_t)bn * CC + t] = d * rsqrtf(var + 1e-5f) * g1[t] + b1[t];
}

// ============================================================
// Kernel 2: LayerNorm2 (same, no projection)
// ============================================================
__global__ __launch_bounds__(128) void ln2_k(
    const float* __restrict__ hin, const float* __restrict__ g2, const float* __restrict__ b2,
    float* __restrict__ h2) {
  int bn = blockIdx.x;
  __shared__ float red[CC];
  int t = threadIdx.x;
  float acc = hin[(size_t)bn * CC + t];
  red[t] = acc; __syncthreads();
  for (int s = 64; s > 0; s >>= 1) { if (t < s) red[t] += red[t + s]; __syncthreads(); }
  float mu = red[0] * (1.f / CC);
  __syncthreads();
  float d = acc - mu;
  red[t] = d * d; __syncthreads();
  for (int s = 64; s > 0; s >>= 1) { if (t < s) red[t] += red[t + s]; __syncthreads(); }
  float var = red[0] * (1.f / CC);
  h2[(size_t)bn * CC + t] = d * rsqrtf(var + 1e-5f) * g2[t] + b2[t];
}

// ============================================================
// Kernel 3: KNN. One wave per query point; 4 waves per block share an
// LDS copy of the batch's 2048 points. Per-lane register top-16
// (insertion sort, static indices only), then 16 rounds of
// shfl-butterfly argmin across the wave. Neighbor order is irrelevant
// downstream (softmax+sum over k is permutation invariant).
// grid = B * N/4 = 4096, block = 256
// ============================================================
__global__ __launch_bounds__(256) void knn_k(const float* __restrict__ p, int* __restrict__ idxo) {
  __shared__ float px[NN], py[NN], pz[NN];
  int t = threadIdx.x;
  int b = blockIdx.x >> 9;          // 512 groups per batch
  int g = blockIdx.x & 511;
  const float* pb = p + (size_t)b * 3 * NN;
  for (int i = t; i < NN; i += 256) { px[i] = pb[i]; py[i] = pb[NN + i]; pz[i] = pb[2 * NN + i]; }
  __syncthreads();
  int w = t >> 6, lane = t & 63;
  int n = g * 4 + w;
  float pnx = px[n], pny = py[n], pnz = pz[n];
  float bd[16]; int bi[16];
  #pragma unroll
  for (int s = 0; s < 16; ++s) { bd[s] = 3.4e38f; bi[s] = 0x7fffffff; }
  for (int m = lane; m < NN; m += 64) {
    float dx = pnx - px[m], dy = pny - py[m], dz = pnz - pz[m];
    float dist = dx * dx + dy * dy + dz * dz;
    if (m == n) dist = 3.4e38f;
    if (dist < bd[15]) {
      float dv = dist; int di = m;
      #pragma unroll
      for (int s = 0; s < 16; ++s) {
        if (dv < bd[s]) {
          float tf = bd[s]; bd[s] = dv; dv = tf;
          int ti = bi[s]; bi[s] = di; di = ti;
        }
      }
    }
  }
  // 16 rounds of cross-lane argmin extraction (registers + shfl only)
  for (int r = 0; r < 16; ++r) {
    float best = 3.4e38f; int bm = 0x7fffffff;
    #pragma unroll
    for (int s = 0; s < 16; ++s) {
      if (bd[s] < best || (bd[s] == best && bi[s] < bm)) { best = bd[s]; bm = bi[s]; }
    }
    for (int off = 32; off > 0; off >>= 1) {
      float ov = __shfl_xor(best, off);
      int   om = __shfl_xor(bm, off);
      if (ov < best || (ov == best && om < bm)) { best = ov; bm = om; }
    }
    if (lane == 0) idxo[((size_t)b * NN + n) * KNB + r] = bm;
    #pragma unroll
    for (int s = 0; s < 16; ++s) { if (bi[s] == bm) { bd[s] = 3.4e38f; bi[s] = 0x7fffffff; } }
  }
}

// ============================================================
// Kernel 4: generic bf16-MFMA GEMM  C[M,N] = epi(A[M,K] @ W[N,K]^T + bias)
// AKIND: 0 = A fp32, 1 = A bf16.  EPI: 0 plain fp32, 1 relu->bf16,
// 2 +resid and transposed store to [B,C,N].
// block tile 64x64, BK=32. 256 threads = 4 waves; wave w owns n-tile w
// across all 4 m-tiles.
// ============================================================
template<int AKIND, int EPI>
__global__ __launch_bounds__(256) void gemm_k(
    const float* __restrict__ Af, const bf16_t* __restrict__ Ab,
    const float* __restrict__ W, const float* __restrict__ bias,
    float* __restrict__ outF, bf16_t* __restrict__ outB,
    const float* __restrict__ resid,
    int M, int Ncol, int Kdim) {
  __shared__ bf16_t As[64 * 40];   // +8 halfword pad per row: bank spread, keeps 16B align
  __shared__ bf16_t Bs[64 * 40];
  int t = threadIdx.x;
  int lane = t & 63, w = t >> 6, quad = lane >> 4, l15 = lane & 15;
  int mBase = blockIdx.x * 64, nBase = blockIdx.y * 64;
  int r = t >> 2, seg = (t & 3) * 8;
  f32x4 acc[4] = {{0,0,0,0},{0,0,0,0},{0,0,0,0},{0,0,0,0}};
  for (int k0 = 0; k0 < Kdim; k0 += 32) {
    __syncthreads();
    if (AKIND == 0) {
      const float* src = Af + (size_t)(mBase + r) * Kdim + k0 + seg;
      *(bf16x8*)(&As[r * 40 + seg]) = cvt8(src);
    } else {
      const bf16_t* src = Ab + (size_t)(mBase + r) * Kdim + k0 + seg;
      *(bf16x8*)(&As[r * 40 + seg]) = *(const bf16x8*)src;
    }
    {
      const float* src = W + (size_t)(nBase + r) * Kdim + k0 + seg;
      *(bf16x8*)(&Bs[r * 40 + seg]) = cvt8(src);
    }
    __syncthreads();
    bf16x8 bfr = *(const bf16x8*)(&Bs[(w * 16 + l15) * 40 + quad * 8]);
    #pragma unroll
    for (int mt = 0; mt < 4; ++mt) {
      bf16x8 afr = *(const bf16x8*)(&As[(mt * 16 + l15) * 40 + quad * 8]);
      acc[mt] = MFMA16(afr, bfr, acc[mt]);
    }
  }
  int n = nBase + w * 16 + l15;
  float bv = bias ? bias[n] : 0.f;
  #pragma unroll
  for (int mt = 0; mt < 4; ++mt) {
    #pragma unroll
    for (int reg = 0; reg < 4; ++reg) {
      int m = mBase + mt * 16 + quad * 4 + reg;
      float val = acc[mt][reg] + bv;
      if (EPI == 0) {
        outF[(size_t)m * Ncol + n] = val;
      } else if (EPI == 1) {
        outB[(size_t)m * Ncol + n] = (__bf16)fmaxf(val, 0.f);
      } else {
        val += resid[(size_t)m * CC + n];
        int bo = m >> 11, np = m & (NN - 1);
        outF[((size_t)bo * CC + n) * NN + np] = val;
      }
    }
  }
}

// ============================================================
// Kernel 5: fused neighbor attention. One point at a time per block
// (4 points sequentially). 4 waves; wave w owns c-tiles {2w, 2w+1}.
// Wd2^T / Wa^T B-fragments persistent in registers (64 VGPR).
//   t = relu(rel@Wd1^T+bd1)        -> LDS bf16 [16][136]
//   d = t @ Wd2^T + bd2            -> MFMA, kept in regs (C/D layout)
//   u = q - k_j + d                -> LDS bf16 [16][136]
//   logits = u @ Wa^T + ba         -> MFMA
//   softmax over j: 4 regs + shfl_xor(16,32)  (j = quad*4+reg rows)
//   y = sum_j a*(v_j + d); hres = h + y
// ============================================================
__global__ __launch_bounds__(256) void attn_k(
    const float* __restrict__ qbuf, const float* __restrict__ kbuf, const float* __restrict__ vbuf,
    const float* __restrict__ p, const int* __restrict__ idx,
    const float* __restrict__ Wd1, const float* __restrict__ bd1,
    const float* __restrict__ Wd2, const float* __restrict__ bd2,
    const float* __restrict__ Wa, const float* __restrict__ ba,
    const float* __restrict__ h, float* __restrict__ hres) {
  __shared__ bf16_t ts[16 * 136];
  __shared__ bf16_t us[16 * 136];
  __shared__ float kjs[16 * 129];
  __shared__ float vjs[16 * 129];
  __shared__ float qs[CC];
  __shared__ float pjx[16], pjy[16], pjz[16];
  __shared__ int idxs[16];
  int t = threadIdx.x;
  int lane = t & 63, w = t >> 6, quad = lane >> 4, l15 = lane & 15;

  // persistent B-fragments for Wd2 and Wa
  bf16x8 Bd[2][4], Ba[2][4];
  #pragma unroll
  for (int t2 = 0; t2 < 2; ++t2) {
    int row = (w * 2 + t2) * 16 + l15;   // output channel c
    #pragma unroll
    for (int s = 0; s < 4; ++s) {
      Bd[t2][s] = cvt8(Wd2 + (size_t)row * CC + s * 32 + quad * 8);
      Ba[t2][s] = cvt8(Wa  + (size_t)row * CC + s * 32 + quad * 8);
    }
  }

  for (int pt = 0; pt < 4; ++pt) {
    int bn = blockIdx.x * 4 + pt;
    int b = bn >> 11, n = bn & (NN - 1);
    const float* pb = p + (size_t)b * 3 * NN;
    if (t < 16) {
      int jj = idx[(size_t)bn * KNB + t];
      idxs[t] = jj;
      pjx[t] = pb[jj]; pjy[t] = pb[NN + jj]; pjz[t] = pb[2 * NN + jj];
    }
    if (t >= 128) qs[t - 128] = qbuf[(size_t)bn * CC + (t - 128)];
    __syncthreads();
    float pnx = pb[n], pny = pb[NN + n], pnz = pb[2 * NN + n];
    for (int i = t; i < 16 * CC; i += 256) {
      int j = i >> 7, c = i & (CC - 1);
      size_t src = ((size_t)(b * NN + idxs[j])) * CC + c;
      kjs[j * 129 + c] = kbuf[src];
      vjs[j * 129 + c] = vbuf[src];
      float rx = pnx - pjx[j], ry = pny - pjy[j], rz = pnz - pjz[j];
      float tv = fmaf(Wd1[c * 3], rx, fmaf(Wd1[c * 3 + 1], ry, fmaf(Wd1[c * 3 + 2], rz, bd1[c])));
      ts[j * 136 + c] = (__bf16)fmaxf(tv, 0.f);
    }
    __syncthreads();

    // phase 1: d = t @ Wd2^T
    bf16x8 af[4];
    #pragma unroll
    for (int s = 0; s < 4; ++s) af[s] = *(const bf16x8*)(&ts[l15 * 136 + s * 32 + quad * 8]);
    f32x4 accd[2] = {{0,0,0,0},{0,0,0,0}};
    #pragma unroll
    for (int t2 = 0; t2 < 2; ++t2)
      #pragma unroll
      for (int s = 0; s < 4; ++s)
        accd[t2] = MFMA16(af[s], Bd[t2][s], accd[t2]);

    // u = q - k_j + d   (also finalize d with bias, keep in regs)
    #pragma unroll
    for (int t2 = 0; t2 < 2; ++t2) {
      int col = (w * 2 + t2) * 16 + l15;
      float qv = qs[col], b2v = bd2[col];
      #pragma unroll
      for (int reg = 0; reg < 4; ++reg) {
        int row = quad * 4 + reg;
        float dv = accd[t2][reg] + b2v;
        accd[t2][reg] = dv;
        float uv = qv - kjs[row * 129 + col] + dv;
        us[row * 136 + col] = (__bf16)uv;
      }
    }
    __syncthreads();

    // phase 2: logits = u @ Wa^T
    #pragma unroll
    for (int s = 0; s < 4; ++s) af[s] = *(const bf16x8*)(&us[l15 * 136 + s * 32 + quad * 8]);
    f32x4 accl[2] = {{0,0,0,0},{0,0,0,0}};
    #pragma unroll
    for (int t2 = 0; t2 < 2; ++t2)
      #pragma unroll
      for (int s = 0; s < 4; ++s)
        accl[t2] = MFMA16(af[s], Ba[t2][s], accl[t2]);

    // softmax over j (rows) + y reduction, all in registers
    #pragma unroll
    for (int t2 = 0; t2 < 2; ++t2) {
      int col = (w * 2 + t2) * 16 + l15;
      float bav = ba[col];
      float lv0 = accl[t2][0] + bav, lv1 = accl[t2][1] + bav;
      float lv2 = accl[t2][2] + bav, lv3 = accl[t2][3] + bav;
      float mx = fmaxf(fmaxf(lv0, lv1), fmaxf(lv2, lv3));
      mx = fmaxf(mx, __shfl_xor(mx, 16));
      mx = fmaxf(mx, __shfl_xor(mx, 32));
      float e0 = __expf(lv0 - mx), e1 = __expf(lv1 - mx);
      float e2 = __expf(lv2 - mx), e3 = __expf(lv3 - mx);
      float ss = e0 + e1 + e2 + e3;
      ss += __shfl_xor(ss, 16); ss += __shfl_xor(ss, 32);
      int r0 = quad * 4;
      float yv = e0 * (vjs[(r0 + 0) * 129 + col] + accd[t2][0])
               + e1 * (vjs[(r0 + 1) * 129 + col] + accd[t2][1])
               + e2 * (vjs[(r0 + 2) * 129 + col] + accd[t2][2])
               + e3 * (vjs[(r0 + 3) * 129 + col] + accd[t2][3]);
      yv += __shfl_xor(yv, 16); yv += __shfl_xor(yv, 32);
      if (quad == 0) hres[(size_t)bn * CC + col] = h[(size_t)bn * CC + col] + yv / ss;
    }
    __syncthreads();
  }
}

// ============================================================
extern "C" void kernel_launch(void* const* d_in, const int* in_sizes, int n_in,
                              void* d_out, int out_size, void* d_ws, size_t ws_size,
                              hipStream_t stream) {
  const float* x   = (const float*)d_in[0];
  const float* p   = (const float*)d_in[1];
  const float* Win = (const float*)d_in[2];
  const float* bin = (const float*)d_in[3];
  const float* Wq  = (const float*)d_in[4];
  const float* Wk  = (const float*)d_in[5];
  const float* Wv  = (const float*)d_in[6];
  const float* Wd1 = (const float*)d_in[7];
  const float* bd1 = (const float*)d_in[8];
  const float* Wd2 = (const float*)d_in[9];
  const float* bd2 = (const float*)d_in[10];
  const float* Wa  = (const float*)d_in[11];
  const float* ba  = (const float*)d_in[12];
  const float* g1  = (const float*)d_in[13];
  const float* b1  = (const float*)d_in[14];
  const float* g2  = (const float*)d_in[15];
  const float* b2  = (const float*)d_in[16];
  const float* Wf1 = (const float*)d_in[17];
  const float* bf1 = (const float*)d_in[18];
  const float* Wf2 = (const float*)d_in[19];
  const float* bf2 = (const float*)d_in[20];
  float* out = (float*)d_out;

  // workspace layout (41 MB):
  //   h[2M] | hn/hres[2M] | q[2M] (->h2) | kb[2M] (->g lo) | vb[2M] (->g hi) | idx[256K int]
  const size_t SZ = (size_t)BNT * CC;   // 2,097,152 floats
  float* wsf = (float*)d_ws;
  float*  h    = wsf;
  float*  hn   = wsf + SZ;       // later reused as hres
  float*  q    = wsf + 2 * SZ;   // later reused as h2
  float*  kb   = wsf + 3 * SZ;   // later reused (with vb) as g (bf16, 16 MB)
  float*  vb   = wsf + 4 * SZ;
  float*  h2   = q;
  bf16_t* g    = (bf16_t*)kb;
  int*    idxw = (int*)(wsf + 5 * SZ);

  inproj_ln_k<<<BNT, 128, 0, stream>>>(x, Win, bin, g1, b1, h, hn);
  knn_k<<<BB * (NN / 4), 256, 0, stream>>>(p, idxw);
  gemm_k<0, 0><<<dim3(BNT / 64, 2), 256, 0, stream>>>(hn, nullptr, Wq, nullptr, q,  nullptr, nullptr, BNT, CC, CC);
  gemm_k<0, 0><<<dim3(BNT / 64, 2), 256, 0, stream>>>(hn, nullptr, Wk, nullptr, kb, nullptr, nullptr, BNT, CC, CC);
  gemm_k<0, 0><<<dim3(BNT / 64, 2), 256, 0, stream>>>(hn, nullptr, Wv, nullptr, vb, nullptr, nullptr, BNT, CC, CC);
  attn_k<<<BNT / 4, 256, 0, stream>>>(q, kb, vb, p, idxw, Wd1, bd1, Wd2, bd2, Wa, ba, h, hn);
  ln2_k<<<BNT, 128, 0, stream>>>(hn, g2, b2, h2);
  gemm_k<0, 1><<<dim3(BNT / 64, 8), 256, 0, stream>>>(h2, nullptr, Wf1, bf1, nullptr, g, nullptr, BNT, 4 * CC, CC);
  gemm_k<1, 2><<<dim3(BNT / 64, 2), 256, 0, stream>>>(nullptr, g, Wf2, bf2, out, nullptr, hn, BNT, CC, 4 * CC);
}

// Round 3
// 476.254 us; speedup vs baseline: 1.8184x; 1.8184x over previous
//
#include <hip/hip_runtime.h>

typedef __bf16 bf16_t;
typedef __bf16 bf16x8 __attribute__((ext_vector_type(8)));
typedef float  f32x4  __attribute__((ext_vector_type(4)));

#define MFMA16(a,b,c) __builtin_amdgcn_mfma_f32_16x16x32_bf16((a),(b),(c),0,0,0)

// ---- constants (problem is fixed-shape) ----
#define BB 8
#define NN 2048
#define CC 128
#define CIN 64
#define KNB 16            // neighbors
#define BNT (BB*NN)       // 16384 points

static __device__ __forceinline__ unsigned umin2(unsigned a, unsigned b) { return a < b ? a : b; }

static __device__ __forceinline__ bf16x8 cvt8(const float* src) {
  f32x4 a0 = *(const f32x4*)src;
  f32x4 a1 = *(const f32x4*)(src + 4);
  bf16x8 fr;
  fr[0] = (__bf16)a0[0]; fr[1] = (__bf16)a0[1]; fr[2] = (__bf16)a0[2]; fr[3] = (__bf16)a0[3];
  fr[4] = (__bf16)a1[0]; fr[5] = (__bf16)a1[1]; fr[6] = (__bf16)a1[2]; fr[7] = (__bf16)a1[3];
  return fr;
}

// ============================================================
// Kernel 1: in_proj (Win @ x_col + bin) fused with LayerNorm1.
// ============================================================
__global__ __launch_bounds__(128) void inproj_ln_k(
    const float* __restrict__ x, const float* __restrict__ Win, const float* __restrict__ bin,
    const float* __restrict__ g1, const float* __restrict__ b1,
    float* __restrict__ h, float* __restrict__ hn) {
  int bn = blockIdx.x;
  int b = bn >> 11, n = bn & (NN - 1);
  __shared__ float xs[CIN];
  __shared__ float red[CC];
  int t = threadIdx.x;
  if (t < CIN) xs[t] = x[((size_t)b * CIN + t) * NN + n];
  __syncthreads();
  float acc = bin[t];
  const float* wr = Win + t * CIN;
  #pragma unroll
  for (int i = 0; i < CIN; i += 4) {
    f32x4 w4 = *(const f32x4*)(wr + i);
    acc += w4[0] * xs[i] + w4[1] * xs[i + 1] + w4[2] * xs[i + 2] + w4[3] * xs[i + 3];
  }
  h[(size_t)bn * CC + t] = acc;
  red[t] = acc; __syncthreads();
  for (int s = 64; s > 0; s >>= 1) { if (t < s) red[t] += red[t + s]; __syncthreads(); }
  float mu = red[0] * (1.f / CC);
  __syncthreads();
  float d = acc - mu;
  red[t] = d * d; __syncthreads();
  for (int s = 64; s > 0; s >>= 1) { if (t < s) red[t] += red[t + s]; __syncthreads(); }
  float var = red[0] * (1.f / CC);
  hn[(size_t)bn * CC + t] = d * rsqrtf(var + 1e-5f) * g1[t] + b1[t];
}

// ============================================================
// Kernel 2: LayerNorm2
// ============================================================
__global__ __launch_bounds__(128) void ln2_k(
    const float* __restrict__ hin, const float* __restrict__ g2, const float* __restrict__ b2,
    float* __restrict__ h2) {
  int bn = blockIdx.x;
  __shared__ float red[CC];
  int t = threadIdx.x;
  float acc = hin[(size_t)bn * CC + t];
  red[t] = acc; __syncthreads();
  for (int s = 64; s > 0; s >>= 1) { if (t < s) red[t] += red[t + s]; __syncthreads(); }
  float mu = red[0] * (1.f / CC);
  __syncthreads();
  float d = acc - mu;
  red[t] = d * d; __syncthreads();
  for (int s = 64; s > 0; s >>= 1) { if (t < s) red[t] += red[t + s]; __syncthreads(); }
  float var = red[0] * (1.f / CC);
  h2[(size_t)bn * CC + t] = d * rsqrtf(var + 1e-5f) * g2[t] + b2[t];
}

// ============================================================
// Kernel 3: KNN, sort-free, EXACT fp32 distances (R2's 5-bit key
// truncation flipped boundary neighbors -> absmax 0.41; reverted).
// One wave per query; 4 waves/block share the batch's points in LDS.
// Each lane holds 32 exact dist-bit keys in registers (positive IEEE
// floats order as uints). Per extraction round:
//   1) per-lane min tree over 32 slots (static indices only)
//   2) shfl-xor butterfly -> exact global min gm
//   3) per-lane descending scan for smallest slot with keys[s]==gm,
//      candidate m = s*64+lane; butterfly-min over m -> smallest
//      global index among exact ties (matches top_k tie order)
//   4) invalidate only the winning slot (static compares)
// grid = B * N/4 = 4096, block = 256
// ============================================================
__global__ __launch_bounds__(256) void knn_k(const float* __restrict__ p, int* __restrict__ idxo) {
  __shared__ float px[NN], py[NN], pz[NN];
  int t = threadIdx.x;
  int b = blockIdx.x >> 9;
  int g = blockIdx.x & 511;
  const float* pb = p + (size_t)b * 3 * NN;
  for (int i = t; i < NN; i += 256) { px[i] = pb[i]; py[i] = pb[NN + i]; pz[i] = pb[2 * NN + i]; }
  __syncthreads();
  int w = t >> 6, lane = t & 63;
  int n = g * 4 + w;
  float pnx = px[n], pny = py[n], pnz = pz[n];
  unsigned keys[32];
  #pragma unroll
  for (int s = 0; s < 32; ++s) {
    int m = s * 64 + lane;
    float dx = pnx - px[m], dy = pny - py[m], dz = pnz - pz[m];
    float dist = dx * dx + dy * dy + dz * dz;
    keys[s] = (m == n) ? 0xFFFFFFFFu : __float_as_uint(dist);
  }
  int* myout = idxo + ((size_t)b * NN + n) * KNB;
  for (int r = 0; r < 16; ++r) {
    // 1) per-lane min over 32 slots
    unsigned t16[16];
    #pragma unroll
    for (int s = 0; s < 16; ++s) t16[s] = umin2(keys[2 * s], keys[2 * s + 1]);
    #pragma unroll
    for (int s = 0; s < 8; ++s) t16[s] = umin2(t16[s], t16[s + 8]);
    #pragma unroll
    for (int s = 0; s < 4; ++s) t16[s] = umin2(t16[s], t16[s + 4]);
    t16[0] = umin2(t16[0], t16[2]); t16[1] = umin2(t16[1], t16[3]);
    unsigned gm = umin2(t16[0], t16[1]);
    // 2) wave-wide exact min
    #pragma unroll
    for (int off = 1; off < 64; off <<= 1) gm = umin2(gm, (unsigned)__shfl_xor((int)gm, off));
    // 3) smallest index among slots matching gm
    unsigned m_local = 0x7FFFFFFFu;
    #pragma unroll
    for (int s = 31; s >= 0; --s) if (keys[s] == gm) m_local = (unsigned)(s * 64 + lane);
    unsigned m_win = m_local;
    #pragma unroll
    for (int off = 1; off < 64; off <<= 1) m_win = umin2(m_win, (unsigned)__shfl_xor((int)m_win, off));
    if (lane == 0) myout[r] = (int)m_win;
    // 4) invalidate exactly the winning slot
    #pragma unroll
    for (int s = 0; s < 32; ++s)
      if ((unsigned)(s * 64 + lane) == m_win) keys[s] = 0xFFFFFFFFu;
  }
}

// ============================================================
// GEMM body:  C[M,N] = epi(A[M,K] @ W[N,K]^T + bias)
// AKIND: 0 = A fp32, 1 = A bf16.  EPI: 0 plain fp32, 1 relu->bf16,
// 2 +resid and transposed store to [B,C,N].
// block tile 64x64, BK=32. 256 threads = 4 waves; wave w owns n-tile w.
// ============================================================
template<int AKIND, int EPI>
static __device__ __forceinline__ void gemm_body(
    const float* __restrict__ Af, const bf16_t* __restrict__ Ab,
    const float* __restrict__ W, const float* __restrict__ bias,
    float* __restrict__ outF, bf16_t* __restrict__ outB,
    const float* __restrict__ resid,
    int mBase, int nBase, int Ncol, int Kdim) {
  __shared__ bf16_t As[64 * 40];
  __shared__ bf16_t Bs[64 * 40];
  int t = threadIdx.x;
  int lane = t & 63, w = t >> 6, quad = lane >> 4, l15 = lane & 15;
  int r = t >> 2, seg = (t & 3) * 8;
  f32x4 acc[4] = {{0,0,0,0},{0,0,0,0},{0,0,0,0},{0,0,0,0}};
  for (int k0 = 0; k0 < Kdim; k0 += 32) {
    __syncthreads();
    if (AKIND == 0) {
      const float* src = Af + (size_t)(mBase + r) * Kdim + k0 + seg;
      *(bf16x8*)(&As[r * 40 + seg]) = cvt8(src);
    } else {
      const bf16_t* src = Ab + (size_t)(mBase + r) * Kdim + k0 + seg;
      *(bf16x8*)(&As[r * 40 + seg]) = *(const bf16x8*)src;
    }
    {
      const float* src = W + (size_t)(nBase + r) * Kdim + k0 + seg;
      *(bf16x8*)(&Bs[r * 40 + seg]) = cvt8(src);
    }
    __syncthreads();
    bf16x8 bfr = *(const bf16x8*)(&Bs[(w * 16 + l15) * 40 + quad * 8]);
    #pragma unroll
    for (int mt = 0; mt < 4; ++mt) {
      bf16x8 afr = *(const bf16x8*)(&As[(mt * 16 + l15) * 40 + quad * 8]);
      acc[mt] = MFMA16(afr, bfr, acc[mt]);
    }
  }
  int n = nBase + w * 16 + l15;
  float bv = bias ? bias[n] : 0.f;
  #pragma unroll
  for (int mt = 0; mt < 4; ++mt) {
    #pragma unroll
    for (int reg = 0; reg < 4; ++reg) {
      int m = mBase + mt * 16 + quad * 4 + reg;
      float val = acc[mt][reg] + bv;
      if (EPI == 0) {
        outF[(size_t)m * Ncol + n] = val;
      } else if (EPI == 1) {
        outB[(size_t)m * Ncol + n] = (__bf16)fmaxf(val, 0.f);
      } else {
        val += resid[(size_t)m * CC + n];
        int bo = m >> 11, np = m & (NN - 1);
        outF[((size_t)bo * CC + n) * NN + np] = val;
      }
    }
  }
}

template<int AKIND, int EPI>
__global__ __launch_bounds__(256) void gemm_k(
    const float* __restrict__ Af, const bf16_t* __restrict__ Ab,
    const float* __restrict__ W, const float* __restrict__ bias,
    float* __restrict__ outF, bf16_t* __restrict__ outB,
    const float* __restrict__ resid,
    int M, int Ncol, int Kdim) {
  gemm_body<AKIND, EPI>(Af, Ab, W, bias, outF, outB, resid,
                        blockIdx.x * 64, blockIdx.y * 64, Ncol, Kdim);
}

// fused q/k/v: blockIdx.y in [0,6), sel = y>>1 picks {Wq,Wk,Wv}
__global__ __launch_bounds__(256) void gemm_qkv_k(
    const float* __restrict__ hn,
    const float* __restrict__ Wq, const float* __restrict__ Wk, const float* __restrict__ Wv,
    float* __restrict__ q, float* __restrict__ kb, float* __restrict__ vb) {
  int sel = blockIdx.y >> 1;
  const float* W = sel == 0 ? Wq : sel == 1 ? Wk : Wv;
  float* out = sel == 0 ? q : sel == 1 ? kb : vb;
  gemm_body<0, 0>(hn, nullptr, W, nullptr, out, nullptr, nullptr,
                  blockIdx.x * 64, (blockIdx.y & 1) * 64, CC, CC);
}

// ============================================================
// Kernel 5: fused neighbor attention.
// ============================================================
__global__ __launch_bounds__(256) void attn_k(
    const float* __restrict__ qbuf, const float* __restrict__ kbuf, const float* __restrict__ vbuf,
    const float* __restrict__ p, const int* __restrict__ idx,
    const float* __restrict__ Wd1, const float* __restrict__ bd1,
    const float* __restrict__ Wd2, const float* __restrict__ bd2,
    const float* __restrict__ Wa, const float* __restrict__ ba,
    const float* __restrict__ h, float* __restrict__ hres) {
  __shared__ bf16_t ts[16 * 136];
  __shared__ bf16_t us[16 * 136];
  __shared__ float kjs[16 * 129];
  __shared__ float vjs[16 * 129];
  __shared__ float qs[CC];
  __shared__ float pjx[16], pjy[16], pjz[16];
  __shared__ int idxs[16];
  int t = threadIdx.x;
  int lane = t & 63, w = t >> 6, quad = lane >> 4, l15 = lane & 15;

  bf16x8 Bd[2][4], Ba[2][4];
  #pragma unroll
  for (int t2 = 0; t2 < 2; ++t2) {
    int row = (w * 2 + t2) * 16 + l15;
    #pragma unroll
    for (int s = 0; s < 4; ++s) {
      Bd[t2][s] = cvt8(Wd2 + (size_t)row * CC + s * 32 + quad * 8);
      Ba[t2][s] = cvt8(Wa  + (size_t)row * CC + s * 32 + quad * 8);
    }
  }

  for (int pt = 0; pt < 4; ++pt) {
    int bn = blockIdx.x * 4 + pt;
    int b = bn >> 11, n = bn & (NN - 1);
    const float* pb = p + (size_t)b * 3 * NN;
    if (t < 16) {
      int jj = idx[(size_t)bn * KNB + t];
      idxs[t] = jj;
      pjx[t] = pb[jj]; pjy[t] = pb[NN + jj]; pjz[t] = pb[2 * NN + jj];
    }
    if (t >= 128) qs[t - 128] = qbuf[(size_t)bn * CC + (t - 128)];
    __syncthreads();
    float pnx = pb[n], pny = pb[NN + n], pnz = pb[2 * NN + n];
    for (int i = t; i < 16 * CC; i += 256) {
      int j = i >> 7, c = i & (CC - 1);
      size_t src = ((size_t)(b * NN + idxs[j])) * CC + c;
      kjs[j * 129 + c] = kbuf[src];
      vjs[j * 129 + c] = vbuf[src];
      float rx = pnx - pjx[j], ry = pny - pjy[j], rz = pnz - pjz[j];
      float tv = fmaf(Wd1[c * 3], rx, fmaf(Wd1[c * 3 + 1], ry, fmaf(Wd1[c * 3 + 2], rz, bd1[c])));
      ts[j * 136 + c] = (__bf16)fmaxf(tv, 0.f);
    }
    __syncthreads();

    bf16x8 af[4];
    #pragma unroll
    for (int s = 0; s < 4; ++s) af[s] = *(const bf16x8*)(&ts[l15 * 136 + s * 32 + quad * 8]);
    f32x4 accd[2] = {{0,0,0,0},{0,0,0,0}};
    #pragma unroll
    for (int t2 = 0; t2 < 2; ++t2)
      #pragma unroll
      for (int s = 0; s < 4; ++s)
        accd[t2] = MFMA16(af[s], Bd[t2][s], accd[t2]);

    #pragma unroll
    for (int t2 = 0; t2 < 2; ++t2) {
      int col = (w * 2 + t2) * 16 + l15;
      float qv = qs[col], b2v = bd2[col];
      #pragma unroll
      for (int reg = 0; reg < 4; ++reg) {
        int row = quad * 4 + reg;
        float dv = accd[t2][reg] + b2v;
        accd[t2][reg] = dv;
        float uv = qv - kjs[row * 129 + col] + dv;
        us[row * 136 + col] = (__bf16)uv;
      }
    }
    __syncthreads();

    #pragma unroll
    for (int s = 0; s < 4; ++s) af[s] = *(const bf16x8*)(&us[l15 * 136 + s * 32 + quad * 8]);
    f32x4 accl[2] = {{0,0,0,0},{0,0,0,0}};
    #pragma unroll
    for (int t2 = 0; t2 < 2; ++t2)
      #pragma unroll
      for (int s = 0; s < 4; ++s)
        accl[t2] = MFMA16(af[s], Ba[t2][s], accl[t2]);

    #pragma unroll
    for (int t2 = 0; t2 < 2; ++t2) {
      int col = (w * 2 + t2) * 16 + l15;
      float bav = ba[col];
      float lv0 = accl[t2][0] + bav, lv1 = accl[t2][1] + bav;
      float lv2 = accl[t2][2] + bav, lv3 = accl[t2][3] + bav;
      float mx = fmaxf(fmaxf(lv0, lv1), fmaxf(lv2, lv3));
      mx = fmaxf(mx, __shfl_xor(mx, 16));
      mx = fmaxf(mx, __shfl_xor(mx, 32));
      float e0 = __expf(lv0 - mx), e1 = __expf(lv1 - mx);
      float e2 = __expf(lv2 - mx), e3 = __expf(lv3 - mx);
      float ss = e0 + e1 + e2 + e3;
      ss += __shfl_xor(ss, 16); ss += __shfl_xor(ss, 32);
      int r0 = quad * 4;
      float yv = e0 * (vjs[(r0 + 0) * 129 + col] + accd[t2][0])
               + e1 * (vjs[(r0 + 1) * 129 + col] + accd[t2][1])
               + e2 * (vjs[(r0 + 2) * 129 + col] + accd[t2][2])
               + e3 * (vjs[(r0 + 3) * 129 + col] + accd[t2][3]);
      yv += __shfl_xor(yv, 16); yv += __shfl_xor(yv, 32);
      if (quad == 0) hres[(size_t)bn * CC + col] = h[(size_t)bn * CC + col] + yv / ss;
    }
    __syncthreads();
  }
}

// ============================================================
extern "C" void kernel_launch(void* const* d_in, const int* in_sizes, int n_in,
                              void* d_out, int out_size, void* d_ws, size_t ws_size,
                              hipStream_t stream) {
  const float* x   = (const float*)d_in[0];
  const float* p   = (const float*)d_in[1];
  const float* Win = (const float*)d_in[2];
  const float* bin = (const float*)d_in[3];
  const float* Wq  = (const float*)d_in[4];
  const float* Wk  = (const float*)d_in[5];
  const float* Wv  = (const float*)d_in[6];
  const float* Wd1 = (const float*)d_in[7];
  const float* bd1 = (const float*)d_in[8];
  const float* Wd2 = (const float*)d_in[9];
  const float* bd2 = (const float*)d_in[10];
  const float* Wa  = (const float*)d_in[11];
  const float* ba  = (const float*)d_in[12];
  const float* g1  = (const float*)d_in[13];
  const float* b1  = (const float*)d_in[14];
  const float* g2  = (const float*)d_in[15];
  const float* b2  = (const float*)d_in[16];
  const float* Wf1 = (const float*)d_in[17];
  const float* bf1 = (const float*)d_in[18];
  const float* Wf2 = (const float*)d_in[19];
  const float* bf2 = (const float*)d_in[20];
  float* out = (float*)d_out;

  const size_t SZ = (size_t)BNT * CC;
  float* wsf = (float*)d_ws;
  float*  h    = wsf;
  float*  hn   = wsf + SZ;       // later reused as hres
  float*  q    = wsf + 2 * SZ;   // later reused as h2
  float*  kb   = wsf + 3 * SZ;   // later reused (with vb) as g (bf16)
  float*  vb   = wsf + 4 * SZ;
  float*  h2   = q;
  bf16_t* g    = (bf16_t*)kb;
  int*    idxw = (int*)(wsf + 5 * SZ);

  inproj_ln_k<<<BNT, 128, 0, stream>>>(x, Win, bin, g1, b1, h, hn);
  knn_k<<<BB * (NN / 4), 256, 0, stream>>>(p, idxw);
  gemm_qkv_k<<<dim3(BNT / 64, 6), 256, 0, stream>>>(hn, Wq, Wk, Wv, q, kb, vb);
  attn_k<<<BNT / 4, 256, 0, stream>>>(q, kb, vb, p, idxw, Wd1, bd1, Wd2, bd2, Wa, ba, h, hn);
  ln2_k<<<BNT, 128, 0, stream>>>(hn, g2, b2, h2);
  gemm_k<0, 1><<<dim3(BNT / 64, 8), 256, 0, stream>>>(h2, nullptr, Wf1, bf1, nullptr, g, nullptr, BNT, 4 * CC, CC);
  gemm_k<1, 2><<<dim3(BNT / 64, 2), 256, 0, stream>>>(nullptr, g, Wf2, bf2, out, nullptr, hn, BNT, CC, 4 * CC);
}

// Round 4
// 345.474 us; speedup vs baseline: 2.5068x; 1.3786x over previous
//
#include <hip/hip_runtime.h>

typedef __bf16 bf16_t;
typedef __bf16 bf16x8 __attribute__((ext_vector_type(8)));
typedef __bf16 bf16x2 __attribute__((ext_vector_type(2)));
typedef float  f32x4  __attribute__((ext_vector_type(4)));

#define MFMA16(a,b,c) __builtin_amdgcn_mfma_f32_16x16x32_bf16((a),(b),(c),0,0,0)

// ---- constants (problem is fixed-shape) ----
#define BB 8
#define NN 2048
#define CC 128
#define CIN 64
#define KNB 16            // neighbors
#define BNT (BB*NN)       // 16384 points

static __device__ __forceinline__ unsigned umin2(unsigned a, unsigned b) { return a < b ? a : b; }

static __device__ __forceinline__ bf16x8 cvt8(const float* src) {
  f32x4 a0 = *(const f32x4*)src;
  f32x4 a1 = *(const f32x4*)(src + 4);
  bf16x8 fr;
  fr[0] = (__bf16)a0[0]; fr[1] = (__bf16)a0[1]; fr[2] = (__bf16)a0[2]; fr[3] = (__bf16)a0[3];
  fr[4] = (__bf16)a1[0]; fr[5] = (__bf16)a1[1]; fr[6] = (__bf16)a1[2]; fr[7] = (__bf16)a1[3];
  return fr;
}

// ============================================================
// Kernel 1: in_proj + LN1, MFMA-based.
// Block = 64 points (one batch each), full N=128 outputs, K=64.
// x[b][cin][n] tile read COALESCED (f32x4 rows), transposed into LDS
// (R3's per-point kernel did 64 strided 4B loads/point — latency bound).
// Epilogue: h fp32 tile -> LDS, per-row LN (4 threads/row + shfl),
// writes h fp32 (residual) and hn bf16 (qkv A input).
// grid = BNT/64 = 256, block = 256
// ============================================================
__global__ __launch_bounds__(256) void inproj_ln_k(
    const float* __restrict__ x, const float* __restrict__ Win, const float* __restrict__ bin,
    const float* __restrict__ g1, const float* __restrict__ b1,
    float* __restrict__ h, bf16_t* __restrict__ hnb) {
  __shared__ bf16_t As[64 * 72];
  __shared__ bf16_t Bs[128 * 72];
  __shared__ float hs[64 * 132];
  int t = threadIdx.x;
  int lane = t & 63, w = t >> 6, quad = lane >> 4, l15 = lane & 15;
  int mBase = blockIdx.x * 64;
  int b = mBase >> 11, n0 = mBase & (NN - 1);
  const float* xb = x + (size_t)b * CIN * NN;
  // stage A transposed: As[m][k] = x[b][k][n0+m]
  {
    int k = t >> 2, part = t & 3;
    #pragma unroll
    for (int i = 0; i < 4; ++i) {
      f32x4 v = *(const f32x4*)(xb + (size_t)k * NN + n0 + part * 16 + i * 4);
      #pragma unroll
      for (int j2 = 0; j2 < 4; ++j2) As[(part * 16 + i * 4 + j2) * 72 + k] = (__bf16)v[j2];
    }
  }
  // stage B: Win[128][64]
  {
    int row = t >> 1, seg = (t & 1) * 32;
    #pragma unroll
    for (int i = 0; i < 4; ++i)
      *(bf16x8*)(&Bs[row * 72 + seg + i * 8]) = cvt8(Win + (size_t)row * CIN + seg + i * 8);
  }
  __syncthreads();
  f32x4 acc[2][4] = {};
  #pragma unroll
  for (int s = 0; s < 2; ++s) {
    bf16x8 af[4];
    #pragma unroll
    for (int mt = 0; mt < 4; ++mt)
      af[mt] = *(const bf16x8*)(&As[(mt * 16 + l15) * 72 + s * 32 + quad * 8]);
    #pragma unroll
    for (int t2 = 0; t2 < 2; ++t2) {
      bf16x8 bfr = *(const bf16x8*)(&Bs[((w * 2 + t2) * 16 + l15) * 72 + s * 32 + quad * 8]);
      #pragma unroll
      for (int mt = 0; mt < 4; ++mt) acc[t2][mt] = MFMA16(af[mt], bfr, acc[t2][mt]);
    }
  }
  #pragma unroll
  for (int t2 = 0; t2 < 2; ++t2) {
    int col = (w * 2 + t2) * 16 + l15;
    float bv = bin[col];
    #pragma unroll
    for (int mt = 0; mt < 4; ++mt)
      #pragma unroll
      for (int reg = 0; reg < 4; ++reg)
        hs[(mt * 16 + quad * 4 + reg) * 132 + col] = acc[t2][mt][reg] + bv;
  }
  __syncthreads();
  // LN1: thread t handles (row = t>>2, 32 cols)
  {
    int row = t >> 2, c0 = (t & 3) * 32;
    float v[32];
    #pragma unroll
    for (int i = 0; i < 8; ++i) *(f32x4*)(v + i * 4) = *(const f32x4*)(&hs[row * 132 + c0 + i * 4]);
    float s1 = 0.f, s2 = 0.f;
    #pragma unroll
    for (int i = 0; i < 32; ++i) { s1 += v[i]; s2 += v[i] * v[i]; }
    s1 += __shfl_xor(s1, 1); s1 += __shfl_xor(s1, 2);
    s2 += __shfl_xor(s2, 1); s2 += __shfl_xor(s2, 2);
    float mu = s1 * (1.f / CC);
    float var = s2 * (1.f / CC) - mu * mu;
    float rs = rsqrtf(var + 1e-5f);
    float* hrow = h + (size_t)(mBase + row) * CC + c0;
    #pragma unroll
    for (int i = 0; i < 8; ++i) *(f32x4*)(hrow + i * 4) = *(const f32x4*)(v + i * 4);
    bf16_t* hnrow = hnb + (size_t)(mBase + row) * CC + c0;
    #pragma unroll
    for (int i = 0; i < 4; ++i) {
      f32x4 g4a = ((const f32x4*)g1)[(c0 >> 2) + i * 2],     g4b = ((const f32x4*)g1)[(c0 >> 2) + i * 2 + 1];
      f32x4 b4a = ((const f32x4*)b1)[(c0 >> 2) + i * 2],     b4b = ((const f32x4*)b1)[(c0 >> 2) + i * 2 + 1];
      bf16x8 o;
      #pragma unroll
      for (int j = 0; j < 4; ++j) o[j]     = (__bf16)((v[i * 8 + j]     - mu) * rs * g4a[j] + b4a[j]);
      #pragma unroll
      for (int j = 0; j < 4; ++j) o[4 + j] = (__bf16)((v[i * 8 + 4 + j] - mu) * rs * g4b[j] + b4b[j]);
      *(bf16x8*)(hnrow + i * 8) = o;
    }
  }
}

// ============================================================
// Kernel 3: KNN, sort-free, EXACT fp32 distances (unchanged from R3).
// ============================================================
__global__ __launch_bounds__(256) void knn_k(const float* __restrict__ p, int* __restrict__ idxo) {
  __shared__ float px[NN], py[NN], pz[NN];
  int t = threadIdx.x;
  int b = blockIdx.x >> 9;
  int g = blockIdx.x & 511;
  const float* pb = p + (size_t)b * 3 * NN;
  for (int i = t; i < NN; i += 256) { px[i] = pb[i]; py[i] = pb[NN + i]; pz[i] = pb[2 * NN + i]; }
  __syncthreads();
  int w = t >> 6, lane = t & 63;
  int n = g * 4 + w;
  float pnx = px[n], pny = py[n], pnz = pz[n];
  unsigned keys[32];
  #pragma unroll
  for (int s = 0; s < 32; ++s) {
    int m = s * 64 + lane;
    float dx = pnx - px[m], dy = pny - py[m], dz = pnz - pz[m];
    float dist = dx * dx + dy * dy + dz * dz;
    keys[s] = (m == n) ? 0xFFFFFFFFu : __float_as_uint(dist);
  }
  int* myout = idxo + ((size_t)b * NN + n) * KNB;
  for (int r = 0; r < 16; ++r) {
    unsigned t16[16];
    #pragma unroll
    for (int s = 0; s < 16; ++s) t16[s] = umin2(keys[2 * s], keys[2 * s + 1]);
    #pragma unroll
    for (int s = 0; s < 8; ++s) t16[s] = umin2(t16[s], t16[s + 8]);
    #pragma unroll
    for (int s = 0; s < 4; ++s) t16[s] = umin2(t16[s], t16[s + 4]);
    t16[0] = umin2(t16[0], t16[2]); t16[1] = umin2(t16[1], t16[3]);
    unsigned gm = umin2(t16[0], t16[1]);
    #pragma unroll
    for (int off = 1; off < 64; off <<= 1) gm = umin2(gm, (unsigned)__shfl_xor((int)gm, off));
    unsigned m_local = 0x7FFFFFFFu;
    #pragma unroll
    for (int s = 31; s >= 0; --s) if (keys[s] == gm) m_local = (unsigned)(s * 64 + lane);
    unsigned m_win = m_local;
    #pragma unroll
    for (int off = 1; off < 64; off <<= 1) m_win = umin2(m_win, (unsigned)__shfl_xor((int)m_win, off));
    if (lane == 0) myout[r] = (int)m_win;
    #pragma unroll
    for (int s = 0; s < 32; ++s)
      if ((unsigned)(s * 64 + lane) == m_win) keys[s] = 0xFFFFFFFFu;
  }
}

// ============================================================
// GEMM body:  C[M,N] = epi(A[M,K] @ W[N,K]^T + bias), A bf16.
// EPI: 0 fp32 store, 1 relu->bf16, 2 +resid transposed [B,C,N], 3 bf16 store.
// ============================================================
template<int EPI>
static __device__ __forceinline__ void gemm_body(
    const bf16_t* __restrict__ Ab,
    const float* __restrict__ W, const float* __restrict__ bias,
    float* __restrict__ outF, bf16_t* __restrict__ outB,
    const float* __restrict__ resid,
    int mBase, int nBase, int Ncol, int Kdim) {
  __shared__ bf16_t As[64 * 40];
  __shared__ bf16_t Bs[64 * 40];
  int t = threadIdx.x;
  int lane = t & 63, w = t >> 6, quad = lane >> 4, l15 = lane & 15;
  int r = t >> 2, seg = (t & 3) * 8;
  f32x4 acc[4] = {{0,0,0,0},{0,0,0,0},{0,0,0,0},{0,0,0,0}};
  for (int k0 = 0; k0 < Kdim; k0 += 32) {
    __syncthreads();
    *(bf16x8*)(&As[r * 40 + seg]) = *(const bf16x8*)(Ab + (size_t)(mBase + r) * Kdim + k0 + seg);
    *(bf16x8*)(&Bs[r * 40 + seg]) = cvt8(W + (size_t)(nBase + r) * Kdim + k0 + seg);
    __syncthreads();
    bf16x8 bfr = *(const bf16x8*)(&Bs[(w * 16 + l15) * 40 + quad * 8]);
    #pragma unroll
    for (int mt = 0; mt < 4; ++mt) {
      bf16x8 afr = *(const bf16x8*)(&As[(mt * 16 + l15) * 40 + quad * 8]);
      acc[mt] = MFMA16(afr, bfr, acc[mt]);
    }
  }
  int n = nBase + w * 16 + l15;
  float bv = bias ? bias[n] : 0.f;
  #pragma unroll
  for (int mt = 0; mt < 4; ++mt) {
    #pragma unroll
    for (int reg = 0; reg < 4; ++reg) {
      int m = mBase + mt * 16 + quad * 4 + reg;
      float val = acc[mt][reg] + bv;
      if (EPI == 0) {
        outF[(size_t)m * Ncol + n] = val;
      } else if (EPI == 1) {
        outB[(size_t)m * Ncol + n] = (__bf16)fmaxf(val, 0.f);
      } else if (EPI == 3) {
        outB[(size_t)m * Ncol + n] = (__bf16)val;
      } else {
        val += resid[(size_t)m * CC + n];
        int bo = m >> 11, np = m & (NN - 1);
        outF[((size_t)bo * CC + n) * NN + np] = val;
      }
    }
  }
}

template<int EPI>
__global__ __launch_bounds__(256) void gemm_k(
    const bf16_t* __restrict__ Ab,
    const float* __restrict__ W, const float* __restrict__ bias,
    float* __restrict__ outF, bf16_t* __restrict__ outB,
    const float* __restrict__ resid,
    int Ncol, int Kdim) {
  gemm_body<EPI>(Ab, W, bias, outF, outB, resid, blockIdx.x * 64, blockIdx.y * 64, Ncol, Kdim);
}

// fused q/k/v: blockIdx.y in [0,6), sel = y>>1 picks {Wq->q fp32, Wk->kb bf16, Wv->vb bf16}
__global__ __launch_bounds__(256) void gemm_qkv_k(
    const bf16_t* __restrict__ hnb,
    const float* __restrict__ Wq, const float* __restrict__ Wk, const float* __restrict__ Wv,
    float* __restrict__ q, bf16_t* __restrict__ kb, bf16_t* __restrict__ vb) {
  int sel = blockIdx.y >> 1;
  int nB = (blockIdx.y & 1) * 64, mB = blockIdx.x * 64;
  if (sel == 0)      gemm_body<0>(hnb, Wq, nullptr, q, nullptr, nullptr, mB, nB, CC, CC);
  else if (sel == 1) gemm_body<3>(hnb, Wk, nullptr, nullptr, kb, nullptr, mB, nB, CC, CC);
  else               gemm_body<3>(hnb, Wv, nullptr, nullptr, vb, nullptr, mB, nB, CC, CC);
}

// ============================================================
// Kernel 5: fused neighbor attention, BATCHED: 4 points per block as one
// M=64 MFMA pass (m-tile mt == point mt). 6 barriers/block vs R3's 24;
// all 64 rows' k/v gathers in flight at once (bf16 inputs).
// Epilogue fuses LN2: wave w normalizes point w, writes h2 bf16.
// grid = BNT/4 = 4096, block = 256
// ============================================================
__global__ __launch_bounds__(256, 2) void attn_k(
    const float* __restrict__ qbuf, const bf16_t* __restrict__ kbuf, const bf16_t* __restrict__ vbuf,
    const float* __restrict__ p, const int* __restrict__ idx,
    const float* __restrict__ Wd1, const float* __restrict__ bd1,
    const float* __restrict__ Wd2, const float* __restrict__ bd2,
    const float* __restrict__ Wa, const float* __restrict__ ba,
    const float* __restrict__ g2, const float* __restrict__ b2,
    const float* __restrict__ h, float* __restrict__ hres, bf16_t* __restrict__ h2) {
  __shared__ bf16_t ts[64 * 136];      // t-matrix; reused for u
  __shared__ bf16_t kjs[64 * 136];
  __shared__ bf16_t vjs[64 * 136];
  __shared__ float qs[4 * 128];        // reused as hrs in epilogue
  __shared__ f32x4 wd1s[128];          // {Wd1[c][0..2], bd1[c]}
  __shared__ float rels[64 * 3];
  __shared__ int idxs[64];
  int t = threadIdx.x;
  int lane = t & 63, w = t >> 6, quad = lane >> 4, l15 = lane & 15;
  int bn0 = blockIdx.x * 4;
  int b = bn0 >> 11, n0 = bn0 & (NN - 1);
  const float* pb = p + (size_t)b * 3 * NN;

  // persistent B-fragments for Wd2 and Wa (wave w owns c-tiles 2w, 2w+1)
  bf16x8 Bd[2][4], Ba[2][4];
  #pragma unroll
  for (int t2 = 0; t2 < 2; ++t2) {
    int row = (w * 2 + t2) * 16 + l15;
    #pragma unroll
    for (int s = 0; s < 4; ++s) {
      Bd[t2][s] = cvt8(Wd2 + (size_t)row * CC + s * 32 + quad * 8);
      Ba[t2][s] = cvt8(Wa  + (size_t)row * CC + s * 32 + quad * 8);
    }
  }

  // phase 0: idx, rel, q, wd1 staging
  if (t < 64) {
    int jj = idx[(size_t)bn0 * KNB + t];
    idxs[t] = jj;
    int npt = n0 + (t >> 4);
    rels[t * 3 + 0] = pb[npt]          - pb[jj];
    rels[t * 3 + 1] = pb[NN + npt]     - pb[NN + jj];
    rels[t * 3 + 2] = pb[2 * NN + npt] - pb[2 * NN + jj];
  }
  if (t < 128) {
    ((f32x4*)qs)[t] = ((const f32x4*)(qbuf + (size_t)bn0 * CC))[t];
    f32x4 wv;
    wv[0] = Wd1[t * 3]; wv[1] = Wd1[t * 3 + 1]; wv[2] = Wd1[t * 3 + 2]; wv[3] = bd1[t];
    wd1s[t] = wv;
  }
  __syncthreads();

  // phase 1: gather k/v (bf16x8 loads) + compute t = relu(rel@Wd1^T+bd1)
  {
    int rg = t >> 4, cg = t & 15;      // 4 rows each, 8 cols each
    f32x4 wv[8];
    #pragma unroll
    for (int c8 = 0; c8 < 8; ++c8) wv[c8] = wd1s[cg * 8 + c8];
    #pragma unroll
    for (int i = 0; i < 4; ++i) {
      int row = rg * 4 + i;
      int jj = idxs[row];
      size_t base = (size_t)(b * NN + jj) * CC + cg * 8;
      *(bf16x8*)(&kjs[row * 136 + cg * 8]) = *(const bf16x8*)(kbuf + base);
      *(bf16x8*)(&vjs[row * 136 + cg * 8]) = *(const bf16x8*)(vbuf + base);
      float rx = rels[row * 3], ry = rels[row * 3 + 1], rz = rels[row * 3 + 2];
      bf16x8 tf;
      #pragma unroll
      for (int c8 = 0; c8 < 8; ++c8) {
        float tv = fmaf(wv[c8][0], rx, fmaf(wv[c8][1], ry, fmaf(wv[c8][2], rz, wv[c8][3])));
        tf[c8] = (__bf16)fmaxf(tv, 0.f);
      }
      *(bf16x8*)(&ts[row * 136 + cg * 8]) = tf;
    }
  }
  __syncthreads();

  // phase 2: d = t @ Wd2^T  (M=64)
  f32x4 accd[2][4] = {};
  #pragma unroll
  for (int s = 0; s < 4; ++s) {
    bf16x8 af[4];
    #pragma unroll
    for (int mt = 0; mt < 4; ++mt)
      af[mt] = *(const bf16x8*)(&ts[(mt * 16 + l15) * 136 + s * 32 + quad * 8]);
    #pragma unroll
    for (int t2 = 0; t2 < 2; ++t2)
      #pragma unroll
      for (int mt = 0; mt < 4; ++mt)
        accd[t2][mt] = MFMA16(af[mt], Bd[t2][s], accd[t2][mt]);
  }
  __syncthreads();   // all ts reads done before overwrite

  // u = q - k_j + d  -> ts (bf16); finalize d (+bd2) in regs
  #pragma unroll
  for (int t2 = 0; t2 < 2; ++t2) {
    int col = (w * 2 + t2) * 16 + l15;
    float b2v = bd2[col];
    #pragma unroll
    for (int mt = 0; mt < 4; ++mt) {
      float qv = qs[mt * 128 + col];
      #pragma unroll
      for (int reg = 0; reg < 4; ++reg) {
        int row = mt * 16 + quad * 4 + reg;
        float dv = accd[t2][mt][reg] + b2v;
        accd[t2][mt][reg] = dv;
        ts[row * 136 + col] = (__bf16)(qv - (float)kjs[row * 136 + col] + dv);
      }
    }
  }
  __syncthreads();

  // phase 3: logits = u @ Wa^T
  f32x4 accl[2][4] = {};
  #pragma unroll
  for (int s = 0; s < 4; ++s) {
    bf16x8 af[4];
    #pragma unroll
    for (int mt = 0; mt < 4; ++mt)
      af[mt] = *(const bf16x8*)(&ts[(mt * 16 + l15) * 136 + s * 32 + quad * 8]);
    #pragma unroll
    for (int t2 = 0; t2 < 2; ++t2)
      #pragma unroll
      for (int mt = 0; mt < 4; ++mt)
        accl[t2][mt] = MFMA16(af[mt], Ba[t2][s], accl[t2][mt]);
  }

  // phase 4: softmax over j (rows within each point/mt), y, residual
  float* hrs = qs;   // qs dead after u-phase
  #pragma unroll
  for (int t2 = 0; t2 < 2; ++t2) {
    int col = (w * 2 + t2) * 16 + l15;
    float bav = ba[col];
    #pragma unroll
    for (int mt = 0; mt < 4; ++mt) {
      float lv0 = accl[t2][mt][0] + bav, lv1 = accl[t2][mt][1] + bav;
      float lv2 = accl[t2][mt][2] + bav, lv3 = accl[t2][mt][3] + bav;
      float mx = fmaxf(fmaxf(lv0, lv1), fmaxf(lv2, lv3));
      mx = fmaxf(mx, __shfl_xor(mx, 16));
      mx = fmaxf(mx, __shfl_xor(mx, 32));
      float e0 = __expf(lv0 - mx), e1 = __expf(lv1 - mx);
      float e2 = __expf(lv2 - mx), e3 = __expf(lv3 - mx);
      float ss = e0 + e1 + e2 + e3;
      ss += __shfl_xor(ss, 16); ss += __shfl_xor(ss, 32);
      int r0 = mt * 16 + quad * 4;
      float yv = e0 * ((float)vjs[(r0 + 0) * 136 + col] + accd[t2][mt][0])
               + e1 * ((float)vjs[(r0 + 1) * 136 + col] + accd[t2][mt][1])
               + e2 * ((float)vjs[(r0 + 2) * 136 + col] + accd[t2][mt][2])
               + e3 * ((float)vjs[(r0 + 3) * 136 + col] + accd[t2][mt][3]);
      yv += __shfl_xor(yv, 16); yv += __shfl_xor(yv, 32);
      if (quad == 0) {
        float hv = h[(size_t)(bn0 + mt) * CC + col] + yv / ss;
        hres[(size_t)(bn0 + mt) * CC + col] = hv;
        hrs[mt * 128 + col] = hv;
      }
    }
  }
  __syncthreads();

  // fused LN2: wave w normalizes point w, writes h2 bf16
  {
    int c0 = lane * 2;
    float v0 = hrs[w * 128 + c0], v1 = hrs[w * 128 + c0 + 1];
    float s1 = v0 + v1, s2 = v0 * v0 + v1 * v1;
    #pragma unroll
    for (int off = 1; off < 64; off <<= 1) { s1 += __shfl_xor(s1, off); s2 += __shfl_xor(s2, off); }
    float mu = s1 * (1.f / CC);
    float var = s2 * (1.f / CC) - mu * mu;
    float rs = rsqrtf(var + 1e-5f);
    bf16x2 o;
    o[0] = (__bf16)((v0 - mu) * rs * g2[c0] + b2[c0]);
    o[1] = (__bf16)((v1 - mu) * rs * g2[c0 + 1] + b2[c0 + 1]);
    *(bf16x2*)(h2 + (size_t)(bn0 + w) * CC + c0) = o;
  }
}

// ============================================================
extern "C" void kernel_launch(void* const* d_in, const int* in_sizes, int n_in,
                              void* d_out, int out_size, void* d_ws, size_t ws_size,
                              hipStream_t stream) {
  const float* x   = (const float*)d_in[0];
  const float* p   = (const float*)d_in[1];
  const float* Win = (const float*)d_in[2];
  const float* bin = (const float*)d_in[3];
  const float* Wq  = (const float*)d_in[4];
  const float* Wk  = (const float*)d_in[5];
  const float* Wv  = (const float*)d_in[6];
  const float* Wd1 = (const float*)d_in[7];
  const float* bd1 = (const float*)d_in[8];
  const float* Wd2 = (const float*)d_in[9];
  const float* bd2 = (const float*)d_in[10];
  const float* Wa  = (const float*)d_in[11];
  const float* ba  = (const float*)d_in[12];
  const float* g1  = (const float*)d_in[13];
  const float* b1  = (const float*)d_in[14];
  const float* g2  = (const float*)d_in[15];
  const float* b2  = (const float*)d_in[16];
  const float* Wf1 = (const float*)d_in[17];
  const float* bf1 = (const float*)d_in[18];
  const float* Wf2 = (const float*)d_in[19];
  const float* bf2 = (const float*)d_in[20];
  float* out = (float*)d_out;

  // workspace (37 MB):
  //  [0,SZ)      h fp32 (residual 1)
  //  [SZ,2SZ)    hn bf16 (first half) -> later hres fp32 (attn out, FFN2 resid)
  //  [2SZ,4SZ)   q fp32 | kb bf16 | vb bf16  -> later g bf16 (16 MB)
  //  [4SZ,4.5SZ) h2 bf16
  //  [4.5SZ,..)  idx int[BNT*16]
  const size_t SZ = (size_t)BNT * CC;   // 2,097,152
  float* wsf = (float*)d_ws;
  float*  h    = wsf;
  bf16_t* hnb  = (bf16_t*)(wsf + SZ);
  float*  hres = wsf + SZ;
  float*  q    = wsf + 2 * SZ;
  bf16_t* kb   = (bf16_t*)(wsf + 3 * SZ);
  bf16_t* vb   = kb + SZ;
  bf16_t* g    = (bf16_t*)(wsf + 2 * SZ);
  bf16_t* h2   = (bf16_t*)(wsf + 4 * SZ);
  int*    idxw = (int*)(wsf + 4 * SZ + SZ / 2);

  inproj_ln_k<<<BNT / 64, 256, 0, stream>>>(x, Win, bin, g1, b1, h, hnb);
  knn_k<<<BB * (NN / 4), 256, 0, stream>>>(p, idxw);
  gemm_qkv_k<<<dim3(BNT / 64, 6), 256, 0, stream>>>(hnb, Wq, Wk, Wv, q, kb, vb);
  attn_k<<<BNT / 4, 256, 0, stream>>>(q, kb, vb, p, idxw, Wd1, bd1, Wd2, bd2, Wa, ba,
                                      g2, b2, h, hres, h2);
  gemm_k<1><<<dim3(BNT / 64, 8), 256, 0, stream>>>(h2, Wf1, bf1, nullptr, g, nullptr, 4 * CC, CC);
  gemm_k<2><<<dim3(BNT / 64, 2), 256, 0, stream>>>(g, Wf2, bf2, out, nullptr, hres, CC, 4 * CC);
}

// Round 5
// 325.520 us; speedup vs baseline: 2.6605x; 1.0613x over previous
//
#include <hip/hip_runtime.h>

typedef __bf16 bf16_t;
typedef __bf16 bf16x8 __attribute__((ext_vector_type(8)));
typedef __bf16 bf16x2 __attribute__((ext_vector_type(2)));
typedef float  f32x4  __attribute__((ext_vector_type(4)));

#define MFMA16(a,b,c) __builtin_amdgcn_mfma_f32_16x16x32_bf16((a),(b),(c),0,0,0)

// ---- constants (problem is fixed-shape) ----
#define BB 8
#define NN 2048
#define CC 128
#define CIN 64
#define KNB 16            // neighbors
#define BNT (BB*NN)       // 16384 points

static __device__ __forceinline__ unsigned umin2(unsigned a, unsigned b) { return a < b ? a : b; }

static __device__ __forceinline__ bf16x8 cvt8(const float* src) {
  f32x4 a0 = *(const f32x4*)src;
  f32x4 a1 = *(const f32x4*)(src + 4);
  bf16x8 fr;
  fr[0] = (__bf16)a0[0]; fr[1] = (__bf16)a0[1]; fr[2] = (__bf16)a0[2]; fr[3] = (__bf16)a0[3];
  fr[4] = (__bf16)a1[0]; fr[5] = (__bf16)a1[1]; fr[6] = (__bf16)a1[2]; fr[7] = (__bf16)a1[3];
  return fr;
}

// ============================================================
// Kernel 1: in_proj + LN1, MFMA-based (unchanged from R4).
// ============================================================
__global__ __launch_bounds__(256) void inproj_ln_k(
    const float* __restrict__ x, const float* __restrict__ Win, const float* __restrict__ bin,
    const float* __restrict__ g1, const float* __restrict__ b1,
    float* __restrict__ h, bf16_t* __restrict__ hnb) {
  __shared__ bf16_t As[64 * 72];
  __shared__ bf16_t Bs[128 * 72];
  __shared__ float hs[64 * 132];
  int t = threadIdx.x;
  int lane = t & 63, w = t >> 6, quad = lane >> 4, l15 = lane & 15;
  int mBase = blockIdx.x * 64;
  int b = mBase >> 11, n0 = mBase & (NN - 1);
  const float* xb = x + (size_t)b * CIN * NN;
  {
    int k = t >> 2, part = t & 3;
    #pragma unroll
    for (int i = 0; i < 4; ++i) {
      f32x4 v = *(const f32x4*)(xb + (size_t)k * NN + n0 + part * 16 + i * 4);
      #pragma unroll
      for (int j2 = 0; j2 < 4; ++j2) As[(part * 16 + i * 4 + j2) * 72 + k] = (__bf16)v[j2];
    }
  }
  {
    int row = t >> 1, seg = (t & 1) * 32;
    #pragma unroll
    for (int i = 0; i < 4; ++i)
      *(bf16x8*)(&Bs[row * 72 + seg + i * 8]) = cvt8(Win + (size_t)row * CIN + seg + i * 8);
  }
  __syncthreads();
  f32x4 acc[2][4] = {};
  #pragma unroll
  for (int s = 0; s < 2; ++s) {
    bf16x8 af[4];
    #pragma unroll
    for (int mt = 0; mt < 4; ++mt)
      af[mt] = *(const bf16x8*)(&As[(mt * 16 + l15) * 72 + s * 32 + quad * 8]);
    #pragma unroll
    for (int t2 = 0; t2 < 2; ++t2) {
      bf16x8 bfr = *(const bf16x8*)(&Bs[((w * 2 + t2) * 16 + l15) * 72 + s * 32 + quad * 8]);
      #pragma unroll
      for (int mt = 0; mt < 4; ++mt) acc[t2][mt] = MFMA16(af[mt], bfr, acc[t2][mt]);
    }
  }
  #pragma unroll
  for (int t2 = 0; t2 < 2; ++t2) {
    int col = (w * 2 + t2) * 16 + l15;
    float bv = bin[col];
    #pragma unroll
    for (int mt = 0; mt < 4; ++mt)
      #pragma unroll
      for (int reg = 0; reg < 4; ++reg)
        hs[(mt * 16 + quad * 4 + reg) * 132 + col] = acc[t2][mt][reg] + bv;
  }
  __syncthreads();
  {
    int row = t >> 2, c0 = (t & 3) * 32;
    float v[32];
    #pragma unroll
    for (int i = 0; i < 8; ++i) *(f32x4*)(v + i * 4) = *(const f32x4*)(&hs[row * 132 + c0 + i * 4]);
    float s1 = 0.f, s2 = 0.f;
    #pragma unroll
    for (int i = 0; i < 32; ++i) { s1 += v[i]; s2 += v[i] * v[i]; }
    s1 += __shfl_xor(s1, 1); s1 += __shfl_xor(s1, 2);
    s2 += __shfl_xor(s2, 1); s2 += __shfl_xor(s2, 2);
    float mu = s1 * (1.f / CC);
    float var = s2 * (1.f / CC) - mu * mu;
    float rs = rsqrtf(var + 1e-5f);
    float* hrow = h + (size_t)(mBase + row) * CC + c0;
    #pragma unroll
    for (int i = 0; i < 8; ++i) *(f32x4*)(hrow + i * 4) = *(const f32x4*)(v + i * 4);
    bf16_t* hnrow = hnb + (size_t)(mBase + row) * CC + c0;
    #pragma unroll
    for (int i = 0; i < 4; ++i) {
      f32x4 g4a = ((const f32x4*)g1)[(c0 >> 2) + i * 2],     g4b = ((const f32x4*)g1)[(c0 >> 2) + i * 2 + 1];
      f32x4 b4a = ((const f32x4*)b1)[(c0 >> 2) + i * 2],     b4b = ((const f32x4*)b1)[(c0 >> 2) + i * 2 + 1];
      bf16x8 o;
      #pragma unroll
      for (int j = 0; j < 4; ++j) o[j]     = (__bf16)((v[i * 8 + j]     - mu) * rs * g4a[j] + b4a[j]);
      #pragma unroll
      for (int j = 0; j < 4; ++j) o[4 + j] = (__bf16)((v[i * 8 + 4 + j] - mu) * rs * g4b[j] + b4b[j]);
      *(bf16x8*)(hnrow + i * 8) = o;
    }
  }
}

// ============================================================
// Kernel 3: KNN, sort-free, EXACT fp32 distances (unchanged from R3).
// ============================================================
__global__ __launch_bounds__(256) void knn_k(const float* __restrict__ p, int* __restrict__ idxo) {
  __shared__ float px[NN], py[NN], pz[NN];
  int t = threadIdx.x;
  int b = blockIdx.x >> 9;
  int g = blockIdx.x & 511;
  const float* pb = p + (size_t)b * 3 * NN;
  for (int i = t; i < NN; i += 256) { px[i] = pb[i]; py[i] = pb[NN + i]; pz[i] = pb[2 * NN + i]; }
  __syncthreads();
  int w = t >> 6, lane = t & 63;
  int n = g * 4 + w;
  float pnx = px[n], pny = py[n], pnz = pz[n];
  unsigned keys[32];
  #pragma unroll
  for (int s = 0; s < 32; ++s) {
    int m = s * 64 + lane;
    float dx = pnx - px[m], dy = pny - py[m], dz = pnz - pz[m];
    float dist = dx * dx + dy * dy + dz * dz;
    keys[s] = (m == n) ? 0xFFFFFFFFu : __float_as_uint(dist);
  }
  int* myout = idxo + ((size_t)b * NN + n) * KNB;
  for (int r = 0; r < 16; ++r) {
    unsigned t16[16];
    #pragma unroll
    for (int s = 0; s < 16; ++s) t16[s] = umin2(keys[2 * s], keys[2 * s + 1]);
    #pragma unroll
    for (int s = 0; s < 8; ++s) t16[s] = umin2(t16[s], t16[s + 8]);
    #pragma unroll
    for (int s = 0; s < 4; ++s) t16[s] = umin2(t16[s], t16[s + 4]);
    t16[0] = umin2(t16[0], t16[2]); t16[1] = umin2(t16[1], t16[3]);
    unsigned gm = umin2(t16[0], t16[1]);
    #pragma unroll
    for (int off = 1; off < 64; off <<= 1) gm = umin2(gm, (unsigned)__shfl_xor((int)gm, off));
    unsigned m_local = 0x7FFFFFFFu;
    #pragma unroll
    for (int s = 31; s >= 0; --s) if (keys[s] == gm) m_local = (unsigned)(s * 64 + lane);
    unsigned m_win = m_local;
    #pragma unroll
    for (int off = 1; off < 64; off <<= 1) m_win = umin2(m_win, (unsigned)__shfl_xor((int)m_win, off));
    if (lane == 0) myout[r] = (int)m_win;
    #pragma unroll
    for (int s = 0; s < 32; ++s)
      if ((unsigned)(s * 64 + lane) == m_win) keys[s] = 0xFFFFFFFFu;
  }
}

// ============================================================
// GEMM body + kernels (unchanged from R4).
// ============================================================
template<int EPI>
static __device__ __forceinline__ void gemm_body(
    const bf16_t* __restrict__ Ab,
    const float* __restrict__ W, const float* __restrict__ bias,
    float* __restrict__ outF, bf16_t* __restrict__ outB,
    const float* __restrict__ resid,
    int mBase, int nBase, int Ncol, int Kdim) {
  __shared__ bf16_t As[64 * 40];
  __shared__ bf16_t Bs[64 * 40];
  int t = threadIdx.x;
  int lane = t & 63, w = t >> 6, quad = lane >> 4, l15 = lane & 15;
  int r = t >> 2, seg = (t & 3) * 8;
  f32x4 acc[4] = {{0,0,0,0},{0,0,0,0},{0,0,0,0},{0,0,0,0}};
  for (int k0 = 0; k0 < Kdim; k0 += 32) {
    __syncthreads();
    *(bf16x8*)(&As[r * 40 + seg]) = *(const bf16x8*)(Ab + (size_t)(mBase + r) * Kdim + k0 + seg);
    *(bf16x8*)(&Bs[r * 40 + seg]) = cvt8(W + (size_t)(nBase + r) * Kdim + k0 + seg);
    __syncthreads();
    bf16x8 bfr = *(const bf16x8*)(&Bs[(w * 16 + l15) * 40 + quad * 8]);
    #pragma unroll
    for (int mt = 0; mt < 4; ++mt) {
      bf16x8 afr = *(const bf16x8*)(&As[(mt * 16 + l15) * 40 + quad * 8]);
      acc[mt] = MFMA16(afr, bfr, acc[mt]);
    }
  }
  int n = nBase + w * 16 + l15;
  float bv = bias ? bias[n] : 0.f;
  #pragma unroll
  for (int mt = 0; mt < 4; ++mt) {
    #pragma unroll
    for (int reg = 0; reg < 4; ++reg) {
      int m = mBase + mt * 16 + quad * 4 + reg;
      float val = acc[mt][reg] + bv;
      if (EPI == 0) {
        outF[(size_t)m * Ncol + n] = val;
      } else if (EPI == 1) {
        outB[(size_t)m * Ncol + n] = (__bf16)fmaxf(val, 0.f);
      } else if (EPI == 3) {
        outB[(size_t)m * Ncol + n] = (__bf16)val;
      } else {
        val += resid[(size_t)m * CC + n];
        int bo = m >> 11, np = m & (NN - 1);
        outF[((size_t)bo * CC + n) * NN + np] = val;
      }
    }
  }
}

template<int EPI>
__global__ __launch_bounds__(256) void gemm_k(
    const bf16_t* __restrict__ Ab,
    const float* __restrict__ W, const float* __restrict__ bias,
    float* __restrict__ outF, bf16_t* __restrict__ outB,
    const float* __restrict__ resid,
    int Ncol, int Kdim) {
  gemm_body<EPI>(Ab, W, bias, outF, outB, resid, blockIdx.x * 64, blockIdx.y * 64, Ncol, Kdim);
}

__global__ __launch_bounds__(256) void gemm_qkv_k(
    const bf16_t* __restrict__ hnb,
    const float* __restrict__ Wq, const float* __restrict__ Wk, const float* __restrict__ Wv,
    float* __restrict__ q, bf16_t* __restrict__ kb, bf16_t* __restrict__ vb) {
  int sel = blockIdx.y >> 1;
  int nB = (blockIdx.y & 1) * 64, mB = blockIdx.x * 64;
  if (sel == 0)      gemm_body<0>(hnb, Wq, nullptr, q, nullptr, nullptr, mB, nB, CC, CC);
  else if (sel == 1) gemm_body<3>(hnb, Wk, nullptr, nullptr, kb, nullptr, mB, nB, CC, CC);
  else               gemm_body<3>(hnb, Wv, nullptr, nullptr, vb, nullptr, mB, nB, CC, CC);
}

// ============================================================
// Kernel 5: fused neighbor attention, register-gather version.
// R4 was LDS-capped at 2 blocks/CU (57 KB). k, v, q are consumed only at
// C/D-layout positions (one thread each), so gather them STRAIGHT INTO
// REGISTERS (32 bf16 scalars each for k/v, 8 f32 for q) — kjs/vjs/qs LDS
// buffers deleted. Only ts (t -> u A-layout round-trip) remains big.
// LDS ~22.5 KB; lifetimes staggered (Bd/k die before Ba/v live) with
// __launch_bounds__(256,3).
// grid = BNT/4 = 4096, block = 256
// ============================================================
__global__ __launch_bounds__(256, 3) void attn_k(
    const float* __restrict__ qbuf, const bf16_t* __restrict__ kbuf, const bf16_t* __restrict__ vbuf,
    const float* __restrict__ p, const int* __restrict__ idx,
    const float* __restrict__ Wd1, const float* __restrict__ bd1,
    const float* __restrict__ Wd2, const float* __restrict__ bd2,
    const float* __restrict__ Wa, const float* __restrict__ ba,
    const float* __restrict__ g2, const float* __restrict__ b2,
    const float* __restrict__ h, float* __restrict__ hres, bf16_t* __restrict__ h2) {
  __shared__ bf16_t ts[64 * 136];      // t-matrix; reused for u
  __shared__ float hrs[4 * 128];
  __shared__ f32x4 wd1s[128];          // {Wd1[c][0..2], bd1[c]}
  __shared__ float rels[64 * 3];
  __shared__ int idxs[64];
  int t = threadIdx.x;
  int lane = t & 63, w = t >> 6, quad = lane >> 4, l15 = lane & 15;
  int bn0 = blockIdx.x * 4;
  int b = bn0 >> 11, n0 = bn0 & (NN - 1);
  const float* pb = p + (size_t)b * 3 * NN;
  int col0 = (w * 2 + 0) * 16 + l15;
  int col1 = (w * 2 + 1) * 16 + l15;

  // Bd fragments (Wd2), used in phase 2 only
  bf16x8 Bd[2][4];
  #pragma unroll
  for (int t2 = 0; t2 < 2; ++t2) {
    int row = (w * 2 + t2) * 16 + l15;
    #pragma unroll
    for (int s = 0; s < 4; ++s)
      Bd[t2][s] = cvt8(Wd2 + (size_t)row * CC + s * 32 + quad * 8);
  }

  // phase 0: idx, rel, wd1 staging
  if (t < 64) {
    int jj = idx[(size_t)bn0 * KNB + t];
    idxs[t] = jj;
    int npt = n0 + (t >> 4);
    rels[t * 3 + 0] = pb[npt]          - pb[jj];
    rels[t * 3 + 1] = pb[NN + npt]     - pb[NN + jj];
    rels[t * 3 + 2] = pb[2 * NN + npt] - pb[2 * NN + jj];
  }
  if (t < 128) {
    f32x4 wv;
    wv[0] = Wd1[t * 3]; wv[1] = Wd1[t * 3 + 1]; wv[2] = Wd1[t * 3 + 2]; wv[3] = bd1[t];
    wd1s[t] = wv;
  }
  __syncthreads();

  // q direct loads (C/D-layout: 2 cols x 4 points)
  float qv[2][4];
  #pragma unroll
  for (int mt = 0; mt < 4; ++mt) {
    qv[0][mt] = qbuf[(size_t)(bn0 + mt) * CC + col0];
    qv[1][mt] = qbuf[(size_t)(bn0 + mt) * CC + col1];
  }
  // k direct gathers (rows mt*16+quad*4+reg, cols col0/col1)
  float kreg[2][4][4];
  #pragma unroll
  for (int mt = 0; mt < 4; ++mt)
    #pragma unroll
    for (int reg = 0; reg < 4; ++reg) {
      size_t base = (size_t)(b * NN + idxs[mt * 16 + quad * 4 + reg]) * CC;
      kreg[0][mt][reg] = (float)kbuf[base + col0];
      kreg[1][mt][reg] = (float)kbuf[base + col1];
    }

  // phase 1: t = relu(rel@Wd1^T + bd1) -> ts (each thread 4 rows x 8 cols)
  {
    int rg = t >> 4, cg = t & 15;
    f32x4 wv[8];
    #pragma unroll
    for (int c8 = 0; c8 < 8; ++c8) wv[c8] = wd1s[cg * 8 + c8];
    #pragma unroll
    for (int i = 0; i < 4; ++i) {
      int row = rg * 4 + i;
      float rx = rels[row * 3], ry = rels[row * 3 + 1], rz = rels[row * 3 + 2];
      bf16x8 tf;
      #pragma unroll
      for (int c8 = 0; c8 < 8; ++c8) {
        float tv = fmaf(wv[c8][0], rx, fmaf(wv[c8][1], ry, fmaf(wv[c8][2], rz, wv[c8][3])));
        tf[c8] = (__bf16)fmaxf(tv, 0.f);
      }
      *(bf16x8*)(&ts[row * 136 + cg * 8]) = tf;
    }
  }
  __syncthreads();

  // phase 2: d = t @ Wd2^T  (M=64)
  f32x4 accd[2][4] = {};
  #pragma unroll
  for (int s = 0; s < 4; ++s) {
    bf16x8 af[4];
    #pragma unroll
    for (int mt = 0; mt < 4; ++mt)
      af[mt] = *(const bf16x8*)(&ts[(mt * 16 + l15) * 136 + s * 32 + quad * 8]);
    #pragma unroll
    for (int t2 = 0; t2 < 2; ++t2)
      #pragma unroll
      for (int mt = 0; mt < 4; ++mt)
        accd[t2][mt] = MFMA16(af[mt], Bd[t2][s], accd[t2][mt]);
  }
  __syncthreads();   // all ts reads done before overwrite

  // u = q - k_j + d  -> ts (bf16); finalize d (+bd2) in regs
  {
    float b2v0 = bd2[col0], b2v1 = bd2[col1];
    #pragma unroll
    for (int mt = 0; mt < 4; ++mt)
      #pragma unroll
      for (int reg = 0; reg < 4; ++reg) {
        int row = mt * 16 + quad * 4 + reg;
        float d0 = accd[0][mt][reg] + b2v0;
        float d1 = accd[1][mt][reg] + b2v1;
        accd[0][mt][reg] = d0;
        accd[1][mt][reg] = d1;
        ts[row * 136 + col0] = (__bf16)(qv[0][mt] - kreg[0][mt][reg] + d0);
        ts[row * 136 + col1] = (__bf16)(qv[1][mt] - kreg[1][mt][reg] + d1);
      }
  }
  __syncthreads();

  // Ba fragments (Wa) — loaded late so they reuse Bd's registers
  bf16x8 Ba[2][4];
  #pragma unroll
  for (int t2 = 0; t2 < 2; ++t2) {
    int row = (w * 2 + t2) * 16 + l15;
    #pragma unroll
    for (int s = 0; s < 4; ++s)
      Ba[t2][s] = cvt8(Wa + (size_t)row * CC + s * 32 + quad * 8);
  }

  // phase 3: logits = u @ Wa^T
  f32x4 accl[2][4] = {};
  #pragma unroll
  for (int s = 0; s < 4; ++s) {
    bf16x8 af[4];
    #pragma unroll
    for (int mt = 0; mt < 4; ++mt)
      af[mt] = *(const bf16x8*)(&ts[(mt * 16 + l15) * 136 + s * 32 + quad * 8]);
    #pragma unroll
    for (int t2 = 0; t2 < 2; ++t2)
      #pragma unroll
      for (int mt = 0; mt < 4; ++mt)
        accl[t2][mt] = MFMA16(af[mt], Ba[t2][s], accl[t2][mt]);
  }

  // v direct gathers (same positions as k; issued after u-phase so their
  // registers don't overlap kreg's lifetime)
  float vreg[2][4][4];
  #pragma unroll
  for (int mt = 0; mt < 4; ++mt)
    #pragma unroll
    for (int reg = 0; reg < 4; ++reg) {
      size_t base = (size_t)(b * NN + idxs[mt * 16 + quad * 4 + reg]) * CC;
      vreg[0][mt][reg] = (float)vbuf[base + col0];
      vreg[1][mt][reg] = (float)vbuf[base + col1];
    }

  // phase 4: softmax over j (rows within each point/mt), y, residual
  #pragma unroll
  for (int t2 = 0; t2 < 2; ++t2) {
    int col = t2 ? col1 : col0;
    float bav = ba[col];
    #pragma unroll
    for (int mt = 0; mt < 4; ++mt) {
      float lv0 = accl[t2][mt][0] + bav, lv1 = accl[t2][mt][1] + bav;
      float lv2 = accl[t2][mt][2] + bav, lv3 = accl[t2][mt][3] + bav;
      float mx = fmaxf(fmaxf(lv0, lv1), fmaxf(lv2, lv3));
      mx = fmaxf(mx, __shfl_xor(mx, 16));
      mx = fmaxf(mx, __shfl_xor(mx, 32));
      float e0 = __expf(lv0 - mx), e1 = __expf(lv1 - mx);
      float e2 = __expf(lv2 - mx), e3 = __expf(lv3 - mx);
      float ss = e0 + e1 + e2 + e3;
      ss += __shfl_xor(ss, 16); ss += __shfl_xor(ss, 32);
      float yv = e0 * (vreg[t2][mt][0] + accd[t2][mt][0])
               + e1 * (vreg[t2][mt][1] + accd[t2][mt][1])
               + e2 * (vreg[t2][mt][2] + accd[t2][mt][2])
               + e3 * (vreg[t2][mt][3] + accd[t2][mt][3]);
      yv += __shfl_xor(yv, 16); yv += __shfl_xor(yv, 32);
      if (quad == 0) {
        float hv = h[(size_t)(bn0 + mt) * CC + col] + yv / ss;
        hres[(size_t)(bn0 + mt) * CC + col] = hv;
        hrs[mt * 128 + col] = hv;
      }
    }
  }
  __syncthreads();

  // fused LN2: wave w normalizes point w, writes h2 bf16
  {
    int c0 = lane * 2;
    float v0 = hrs[w * 128 + c0], v1 = hrs[w * 128 + c0 + 1];
    float s1 = v0 + v1, s2 = v0 * v0 + v1 * v1;
    #pragma unroll
    for (int off = 1; off < 64; off <<= 1) { s1 += __shfl_xor(s1, off); s2 += __shfl_xor(s2, off); }
    float mu = s1 * (1.f / CC);
    float var = s2 * (1.f / CC) - mu * mu;
    float rs = rsqrtf(var + 1e-5f);
    bf16x2 o;
    o[0] = (__bf16)((v0 - mu) * rs * g2[c0] + b2[c0]);
    o[1] = (__bf16)((v1 - mu) * rs * g2[c0 + 1] + b2[c0 + 1]);
    *(bf16x2*)(h2 + (size_t)(bn0 + w) * CC + c0) = o;
  }
}

// ============================================================
extern "C" void kernel_launch(void* const* d_in, const int* in_sizes, int n_in,
                              void* d_out, int out_size, void* d_ws, size_t ws_size,
                              hipStream_t stream) {
  const float* x   = (const float*)d_in[0];
  const float* p   = (const float*)d_in[1];
  const float* Win = (const float*)d_in[2];
  const float* bin = (const float*)d_in[3];
  const float* Wq  = (const float*)d_in[4];
  const float* Wk  = (const float*)d_in[5];
  const float* Wv  = (const float*)d_in[6];
  const float* Wd1 = (const float*)d_in[7];
  const float* bd1 = (const float*)d_in[8];
  const float* Wd2 = (const float*)d_in[9];
  const float* bd2 = (const float*)d_in[10];
  const float* Wa  = (const float*)d_in[11];
  const float* ba  = (const float*)d_in[12];
  const float* g1  = (const float*)d_in[13];
  const float* b1  = (const float*)d_in[14];
  const float* g2  = (const float*)d_in[15];
  const float* b2  = (const float*)d_in[16];
  const float* Wf1 = (const float*)d_in[17];
  const float* bf1 = (const float*)d_in[18];
  const float* Wf2 = (const float*)d_in[19];
  const float* bf2 = (const float*)d_in[20];
  float* out = (float*)d_out;

  const size_t SZ = (size_t)BNT * CC;   // 2,097,152
  float* wsf = (float*)d_ws;
  float*  h    = wsf;
  bf16_t* hnb  = (bf16_t*)(wsf + SZ);
  float*  hres = wsf + SZ;
  float*  q    = wsf + 2 * SZ;
  bf16_t* kb   = (bf16_t*)(wsf + 3 * SZ);
  bf16_t* vb   = kb + SZ;
  bf16_t* g    = (bf16_t*)(wsf + 2 * SZ);
  bf16_t* h2   = (bf16_t*)(wsf + 4 * SZ);
  int*    idxw = (int*)(wsf + 4 * SZ + SZ / 2);

  inproj_ln_k<<<BNT / 64, 256, 0, stream>>>(x, Win, bin, g1, b1, h, hnb);
  knn_k<<<BB * (NN / 4), 256, 0, stream>>>(p, idxw);
  gemm_qkv_k<<<dim3(BNT / 64, 6), 256, 0, stream>>>(hnb, Wq, Wk, Wv, q, kb, vb);
  attn_k<<<BNT / 4, 256, 0, stream>>>(q, kb, vb, p, idxw, Wd1, bd1, Wd2, bd2, Wa, ba,
                                      g2, b2, h, hres, h2);
  gemm_k<1><<<dim3(BNT / 64, 8), 256, 0, stream>>>(h2, Wf1, bf1, nullptr, g, nullptr, 4 * CC, CC);
  gemm_k<2><<<dim3(BNT / 64, 2), 256, 0, stream>>>(g, Wf2, bf2, out, nullptr, hres, CC, 4 * CC);
}

// Round 6
// 291.843 us; speedup vs baseline: 2.9675x; 1.1154x over previous
//
#include <hip/hip_runtime.h>

typedef __bf16 bf16_t;
typedef __bf16 bf16x8 __attribute__((ext_vector_type(8)));
typedef __bf16 bf16x2 __attribute__((ext_vector_type(2)));
typedef float  f32x4  __attribute__((ext_vector_type(4)));

#define MFMA16(a,b,c) __builtin_amdgcn_mfma_f32_16x16x32_bf16((a),(b),(c),0,0,0)

// ---- constants (problem is fixed-shape) ----
#define BB 8
#define NN 2048
#define CC 128
#define CIN 64
#define KNB 16            // neighbors
#define BNT (BB*NN)       // 16384 points

// XCD affinity: consecutive blockIdx round-robin over 8 XCDs; remap so the
// batch a block works on == blockIdx%8 == its XCD -> per-batch k/v/q/h stay
// in that XCD's L2. Pure relabeling (correctness-neutral if dispatch differs).
static __device__ __forceinline__ int remap256(int x) { return ((x & 7) << 5) | (x >> 3); }

static __device__ __forceinline__ bf16x8 cvt8(const float* src) {
  f32x4 a0 = *(const f32x4*)src;
  f32x4 a1 = *(const f32x4*)(src + 4);
  bf16x8 fr;
  fr[0] = (__bf16)a0[0]; fr[1] = (__bf16)a0[1]; fr[2] = (__bf16)a0[2]; fr[3] = (__bf16)a0[3];
  fr[4] = (__bf16)a1[0]; fr[5] = (__bf16)a1[1]; fr[6] = (__bf16)a1[2]; fr[7] = (__bf16)a1[3];
  return fr;
}

// ============================================================
// Kernel 1: in_proj + LN1, MFMA-based (R4 body + XCD remap).
// ============================================================
__global__ __launch_bounds__(256) void inproj_ln_k(
    const float* __restrict__ x, const float* __restrict__ Win, const float* __restrict__ bin,
    const float* __restrict__ g1, const float* __restrict__ b1,
    float* __restrict__ h, bf16_t* __restrict__ hnb) {
  __shared__ bf16_t As[64 * 72];
  __shared__ bf16_t Bs[128 * 72];
  __shared__ float hs[64 * 132];
  int t = threadIdx.x;
  int lane = t & 63, w = t >> 6, quad = lane >> 4, l15 = lane & 15;
  int mBase = remap256(blockIdx.x) * 64;
  int b = mBase >> 11, n0 = mBase & (NN - 1);
  const float* xb = x + (size_t)b * CIN * NN;
  {
    int k = t >> 2, part = t & 3;
    #pragma unroll
    for (int i = 0; i < 4; ++i) {
      f32x4 v = *(const f32x4*)(xb + (size_t)k * NN + n0 + part * 16 + i * 4);
      #pragma unroll
      for (int j2 = 0; j2 < 4; ++j2) As[(part * 16 + i * 4 + j2) * 72 + k] = (__bf16)v[j2];
    }
  }
  {
    int row = t >> 1, seg = (t & 1) * 32;
    #pragma unroll
    for (int i = 0; i < 4; ++i)
      *(bf16x8*)(&Bs[row * 72 + seg + i * 8]) = cvt8(Win + (size_t)row * CIN + seg + i * 8);
  }
  __syncthreads();
  f32x4 acc[2][4] = {};
  #pragma unroll
  for (int s = 0; s < 2; ++s) {
    bf16x8 af[4];
    #pragma unroll
    for (int mt = 0; mt < 4; ++mt)
      af[mt] = *(const bf16x8*)(&As[(mt * 16 + l15) * 72 + s * 32 + quad * 8]);
    #pragma unroll
    for (int t2 = 0; t2 < 2; ++t2) {
      bf16x8 bfr = *(const bf16x8*)(&Bs[((w * 2 + t2) * 16 + l15) * 72 + s * 32 + quad * 8]);
      #pragma unroll
      for (int mt = 0; mt < 4; ++mt) acc[t2][mt] = MFMA16(af[mt], bfr, acc[t2][mt]);
    }
  }
  #pragma unroll
  for (int t2 = 0; t2 < 2; ++t2) {
    int col = (w * 2 + t2) * 16 + l15;
    float bv = bin[col];
    #pragma unroll
    for (int mt = 0; mt < 4; ++mt)
      #pragma unroll
      for (int reg = 0; reg < 4; ++reg)
        hs[(mt * 16 + quad * 4 + reg) * 132 + col] = acc[t2][mt][reg] + bv;
  }
  __syncthreads();
  {
    int row = t >> 2, c0 = (t & 3) * 32;
    float v[32];
    #pragma unroll
    for (int i = 0; i < 8; ++i) *(f32x4*)(v + i * 4) = *(const f32x4*)(&hs[row * 132 + c0 + i * 4]);
    float s1 = 0.f, s2 = 0.f;
    #pragma unroll
    for (int i = 0; i < 32; ++i) { s1 += v[i]; s2 += v[i] * v[i]; }
    s1 += __shfl_xor(s1, 1); s1 += __shfl_xor(s1, 2);
    s2 += __shfl_xor(s2, 1); s2 += __shfl_xor(s2, 2);
    float mu = s1 * (1.f / CC);
    float var = s2 * (1.f / CC) - mu * mu;
    float rs = rsqrtf(var + 1e-5f);
    float* hrow = h + (size_t)(mBase + row) * CC + c0;
    #pragma unroll
    for (int i = 0; i < 8; ++i) *(f32x4*)(hrow + i * 4) = *(const f32x4*)(v + i * 4);
    bf16_t* hnrow = hnb + (size_t)(mBase + row) * CC + c0;
    #pragma unroll
    for (int i = 0; i < 4; ++i) {
      f32x4 g4a = ((const f32x4*)g1)[(c0 >> 2) + i * 2],     g4b = ((const f32x4*)g1)[(c0 >> 2) + i * 2 + 1];
      f32x4 b4a = ((const f32x4*)b1)[(c0 >> 2) + i * 2],     b4b = ((const f32x4*)b1)[(c0 >> 2) + i * 2 + 1];
      bf16x8 o;
      #pragma unroll
      for (int j = 0; j < 4; ++j) o[j]     = (__bf16)((v[i * 8 + j]     - mu) * rs * g4a[j] + b4a[j]);
      #pragma unroll
      for (int j = 0; j < 4; ++j) o[4 + j] = (__bf16)((v[i * 8 + 4 + j] - mu) * rs * g4b[j] + b4b[j]);
      *(bf16x8*)(hnrow + i * 8) = o;
    }
  }
}

// ============================================================
// Kernel 3: KNN v3. Exact (dist,idx) packed into a positive double:
// hi = fp32 dist bits, lo = index. v_min_f64 = lexicographic pair min
// (positive doubles order as u64), so tie-break = smallest index ==
// jax top_k order. Per lane: 32 candidates -> static Batcher sort-8 x4
// + bitonic keep-low merges -> sorted top-8 (exact). Global: 16 rounds
// of butterfly-min over lane heads + conditional register shift.
// Coverage assumption: top-16 global within union of per-lane top-8
// (P(fail) ~ 1e-6 for random index assignment).
// grid = B * N/4 = 4096, block = 256
// ============================================================
static __device__ __forceinline__ void cas(double& a, double& b) {
  double lo = fmin(a, b), hi = fmax(a, b); a = lo; b = hi;
}
#define S8(K,o) \
  cas(K[o+0],K[o+1]); cas(K[o+2],K[o+3]); cas(K[o+4],K[o+5]); cas(K[o+6],K[o+7]); \
  cas(K[o+0],K[o+2]); cas(K[o+1],K[o+3]); cas(K[o+4],K[o+6]); cas(K[o+5],K[o+7]); \
  cas(K[o+1],K[o+2]); cas(K[o+5],K[o+6]); \
  cas(K[o+0],K[o+4]); cas(K[o+1],K[o+5]); cas(K[o+2],K[o+6]); cas(K[o+3],K[o+7]); \
  cas(K[o+2],K[o+4]); cas(K[o+3],K[o+5]); \
  cas(K[o+1],K[o+2]); cas(K[o+3],K[o+4]); cas(K[o+5],K[o+6]);
#define M8(K,a,b) \
  K[a+0]=fmin(K[a+0],K[b+7]); K[a+1]=fmin(K[a+1],K[b+6]); K[a+2]=fmin(K[a+2],K[b+5]); K[a+3]=fmin(K[a+3],K[b+4]); \
  K[a+4]=fmin(K[a+4],K[b+3]); K[a+5]=fmin(K[a+5],K[b+2]); K[a+6]=fmin(K[a+6],K[b+1]); K[a+7]=fmin(K[a+7],K[b+0]); \
  cas(K[a+0],K[a+4]); cas(K[a+1],K[a+5]); cas(K[a+2],K[a+6]); cas(K[a+3],K[a+7]); \
  cas(K[a+0],K[a+2]); cas(K[a+1],K[a+3]); cas(K[a+4],K[a+6]); cas(K[a+5],K[a+7]); \
  cas(K[a+0],K[a+1]); cas(K[a+2],K[a+3]); cas(K[a+4],K[a+5]); cas(K[a+6],K[a+7]);

__global__ __launch_bounds__(256) void knn_k(const float* __restrict__ p, int* __restrict__ idxo) {
  __shared__ float px[NN], py[NN], pz[NN];
  int t = threadIdx.x;
  int b = blockIdx.x >> 9;
  int g = blockIdx.x & 511;
  const float* pb = p + (size_t)b * 3 * NN;
  for (int i = t; i < NN; i += 256) { px[i] = pb[i]; py[i] = pb[NN + i]; pz[i] = pb[2 * NN + i]; }
  __syncthreads();
  int w = t >> 6, lane = t & 63;
  int n = g * 4 + w;
  float pnx = px[n], pny = py[n], pnz = pz[n];
  double key[32];
  #pragma unroll
  for (int s = 0; s < 32; ++s) {
    int m = s * 64 + lane;
    float dx = pnx - px[m], dy = pny - py[m], dz = pnz - pz[m];
    float dist = dx * dx + dy * dy + dz * dz;
    unsigned db = (m == n) ? 0x7F800000u : __float_as_uint(dist);
    key[s] = __hiloint2double((int)db, m);
  }
  // per-lane exact sorted top-8
  S8(key, 0); S8(key, 8); S8(key, 16); S8(key, 24);
  M8(key, 0, 8); M8(key, 16, 24); M8(key, 0, 16);
  const double DINF = __hiloint2double(0x7F900000, 0);
  int* myout = idxo + ((size_t)b * NN + n) * KNB;
  #pragma unroll 1
  for (int r = 0; r < 16; ++r) {
    double gm = key[0];
    #pragma unroll
    for (int off = 1; off < 64; off <<= 1) {
      double o = __shfl_xor(gm, off);
      gm = fmin(gm, o);
    }
    if (lane == 0) myout[r] = __double2loint(gm);
    bool win = (key[0] == gm);   // unique pair -> exactly one lane
    key[0] = win ? key[1] : key[0];
    key[1] = win ? key[2] : key[1];
    key[2] = win ? key[3] : key[2];
    key[3] = win ? key[4] : key[3];
    key[4] = win ? key[5] : key[4];
    key[5] = win ? key[6] : key[5];
    key[6] = win ? key[7] : key[6];
    key[7] = win ? DINF   : key[7];
  }
}

// ============================================================
// GEMM body + kernels (R4 body + XCD remap on the 256-wide m grid).
// ============================================================
template<int EPI>
static __device__ __forceinline__ void gemm_body(
    const bf16_t* __restrict__ Ab,
    const float* __restrict__ W, const float* __restrict__ bias,
    float* __restrict__ outF, bf16_t* __restrict__ outB,
    const float* __restrict__ resid,
    int mBase, int nBase, int Ncol, int Kdim) {
  __shared__ bf16_t As[64 * 40];
  __shared__ bf16_t Bs[64 * 40];
  int t = threadIdx.x;
  int lane = t & 63, w = t >> 6, quad = lane >> 4, l15 = lane & 15;
  int r = t >> 2, seg = (t & 3) * 8;
  f32x4 acc[4] = {{0,0,0,0},{0,0,0,0},{0,0,0,0},{0,0,0,0}};
  for (int k0 = 0; k0 < Kdim; k0 += 32) {
    __syncthreads();
    *(bf16x8*)(&As[r * 40 + seg]) = *(const bf16x8*)(Ab + (size_t)(mBase + r) * Kdim + k0 + seg);
    *(bf16x8*)(&Bs[r * 40 + seg]) = cvt8(W + (size_t)(nBase + r) * Kdim + k0 + seg);
    __syncthreads();
    bf16x8 bfr = *(const bf16x8*)(&Bs[(w * 16 + l15) * 40 + quad * 8]);
    #pragma unroll
    for (int mt = 0; mt < 4; ++mt) {
      bf16x8 afr = *(const bf16x8*)(&As[(mt * 16 + l15) * 40 + quad * 8]);
      acc[mt] = MFMA16(afr, bfr, acc[mt]);
    }
  }
  int n = nBase + w * 16 + l15;
  float bv = bias ? bias[n] : 0.f;
  #pragma unroll
  for (int mt = 0; mt < 4; ++mt) {
    #pragma unroll
    for (int reg = 0; reg < 4; ++reg) {
      int m = mBase + mt * 16 + quad * 4 + reg;
      float val = acc[mt][reg] + bv;
      if (EPI == 0) {
        outF[(size_t)m * Ncol + n] = val;
      } else if (EPI == 1) {
        outB[(size_t)m * Ncol + n] = (__bf16)fmaxf(val, 0.f);
      } else if (EPI == 3) {
        outB[(size_t)m * Ncol + n] = (__bf16)val;
      } else {
        val += resid[(size_t)m * CC + n];
        int bo = m >> 11, np = m & (NN - 1);
        outF[((size_t)bo * CC + n) * NN + np] = val;
      }
    }
  }
}

template<int EPI>
__global__ __launch_bounds__(256) void gemm_k(
    const bf16_t* __restrict__ Ab,
    const float* __restrict__ W, const float* __restrict__ bias,
    float* __restrict__ outF, bf16_t* __restrict__ outB,
    const float* __restrict__ resid,
    int Ncol, int Kdim) {
  gemm_body<EPI>(Ab, W, bias, outF, outB, resid, remap256(blockIdx.x) * 64, blockIdx.y * 64, Ncol, Kdim);
}

__global__ __launch_bounds__(256) void gemm_qkv_k(
    const bf16_t* __restrict__ hnb,
    const float* __restrict__ Wq, const float* __restrict__ Wk, const float* __restrict__ Wv,
    float* __restrict__ q, bf16_t* __restrict__ kb, bf16_t* __restrict__ vb) {
  int sel = blockIdx.y >> 1;
  int nB = (blockIdx.y & 1) * 64, mB = remap256(blockIdx.x) * 64;
  if (sel == 0)      gemm_body<0>(hnb, Wq, nullptr, q, nullptr, nullptr, mB, nB, CC, CC);
  else if (sel == 1) gemm_body<3>(hnb, Wk, nullptr, nullptr, kb, nullptr, mB, nB, CC, CC);
  else               gemm_body<3>(hnb, Wv, nullptr, nullptr, vb, nullptr, mB, nB, CC, CC);
}

// ============================================================
// Kernel 5: fused neighbor attention v3.
// - batch = blockIdx&7 -> XCD-local k/v/q/h (L2-resident 1MB/batch)
// - t-fragments computed directly in A-layout registers (no ts staging
//   phase; ts LDS holds only u) -> 3 barriers total
// grid = BNT/4 = 4096, block = 256
// ============================================================
__global__ __launch_bounds__(256, 3) void attn_k(
    const float* __restrict__ qbuf, const bf16_t* __restrict__ kbuf, const bf16_t* __restrict__ vbuf,
    const float* __restrict__ p, const int* __restrict__ idx,
    const float* __restrict__ Wd1, const float* __restrict__ bd1,
    const float* __restrict__ Wd2, const float* __restrict__ bd2,
    const float* __restrict__ Wa, const float* __restrict__ ba,
    const float* __restrict__ g2, const float* __restrict__ b2,
    const float* __restrict__ h, float* __restrict__ hres, bf16_t* __restrict__ h2) {
  __shared__ bf16_t ts[64 * 136];      // u matrix only
  __shared__ float hrs[4 * 128];
  __shared__ f32x4 wd1s[128];          // {Wd1[c][0..2], bd1[c]}
  __shared__ f32x4 rels4[64];          // {rx,ry,rz,0}
  __shared__ int idxs[64];
  int t = threadIdx.x;
  int lane = t & 63, w = t >> 6, quad = lane >> 4, l15 = lane & 15;
  int batch = blockIdx.x & 7, grp = blockIdx.x >> 3;
  int bn0 = batch * NN + grp * 4;
  int b = batch;
  const float* pb = p + (size_t)b * 3 * NN;
  int col0 = w * 32 + l15;
  int col1 = w * 32 + 16 + l15;

  // Bd fragments (Wd2): wave w owns c-tiles 2w, 2w+1
  bf16x8 Bd[2][4];
  #pragma unroll
  for (int t2 = 0; t2 < 2; ++t2) {
    int row = w * 32 + t2 * 16 + l15;
    #pragma unroll
    for (int s = 0; s < 4; ++s)
      Bd[t2][s] = cvt8(Wd2 + (size_t)row * CC + s * 32 + quad * 8);
  }

  // phase 0: idx, rel, wd1 staging
  if (t < 64) {
    int jj = idx[(size_t)bn0 * KNB + t];
    idxs[t] = jj;
    int npt = grp * 4 + (t >> 4);
    f32x4 rv;
    rv[0] = pb[npt]          - pb[jj];
    rv[1] = pb[NN + npt]     - pb[NN + jj];
    rv[2] = pb[2 * NN + npt] - pb[2 * NN + jj];
    rv[3] = 0.f;
    rels4[t] = rv;
  }
  if (t < 128) {
    f32x4 wv;
    wv[0] = Wd1[t * 3]; wv[1] = Wd1[t * 3 + 1]; wv[2] = Wd1[t * 3 + 2]; wv[3] = bd1[t];
    wd1s[t] = wv;
  }
  __syncthreads();

  // early q loads + k gathers (in flight during t/MFMA compute)
  float qv[2][4];
  #pragma unroll
  for (int mt = 0; mt < 4; ++mt) {
    qv[0][mt] = qbuf[(size_t)(bn0 + mt) * CC + col0];
    qv[1][mt] = qbuf[(size_t)(bn0 + mt) * CC + col1];
  }
  float kreg[2][4][4];
  #pragma unroll
  for (int mt = 0; mt < 4; ++mt)
    #pragma unroll
    for (int reg = 0; reg < 4; ++reg) {
      size_t base = (size_t)(b * NN + idxs[mt * 16 + quad * 4 + reg]) * CC;
      kreg[0][mt][reg] = (float)kbuf[base + col0];
      kreg[1][mt][reg] = (float)kbuf[base + col1];
    }

  // t-fragments in registers (A-layout: row=mt*16+l15, k=s*32+quad*8+j) + MFMA-d
  f32x4 relv[4];
  #pragma unroll
  for (int mt = 0; mt < 4; ++mt) relv[mt] = rels4[mt * 16 + l15];
  f32x4 accd[2][4] = {};
  #pragma unroll
  for (int s = 0; s < 4; ++s) {
    bf16x8 af[4];
    #pragma unroll
    for (int j = 0; j < 8; ++j) {
      f32x4 wv = wd1s[s * 32 + quad * 8 + j];
      #pragma unroll
      for (int mt = 0; mt < 4; ++mt) {
        float tv = fmaf(wv[0], relv[mt][0], fmaf(wv[1], relv[mt][1], fmaf(wv[2], relv[mt][2], wv[3])));
        af[mt][j] = (__bf16)fmaxf(tv, 0.f);
      }
    }
    #pragma unroll
    for (int t2 = 0; t2 < 2; ++t2)
      #pragma unroll
      for (int mt = 0; mt < 4; ++mt)
        accd[t2][mt] = MFMA16(af[mt], Bd[t2][s], accd[t2][mt]);
  }

  // u = q - k_j + d -> ts (bf16, C-layout positions); finalize d (+bd2)
  {
    float b2v0 = bd2[col0], b2v1 = bd2[col1];
    #pragma unroll
    for (int mt = 0; mt < 4; ++mt)
      #pragma unroll
      for (int reg = 0; reg < 4; ++reg) {
        int row = mt * 16 + quad * 4 + reg;
        float d0 = accd[0][mt][reg] + b2v0;
        float d1 = accd[1][mt][reg] + b2v1;
        accd[0][mt][reg] = d0;
        accd[1][mt][reg] = d1;
        ts[row * 136 + col0] = (__bf16)(qv[0][mt] - kreg[0][mt][reg] + d0);
        ts[row * 136 + col1] = (__bf16)(qv[1][mt] - kreg[1][mt][reg] + d1);
      }
  }
  __syncthreads();

  // early v/h gathers + Ba fragments (reuse Bd's registers)
  float vreg[2][4][4];
  #pragma unroll
  for (int mt = 0; mt < 4; ++mt)
    #pragma unroll
    for (int reg = 0; reg < 4; ++reg) {
      size_t base = (size_t)(b * NN + idxs[mt * 16 + quad * 4 + reg]) * CC;
      vreg[0][mt][reg] = (float)vbuf[base + col0];
      vreg[1][mt][reg] = (float)vbuf[base + col1];
    }
  float hv[2][4];
  if (quad == 0) {
    #pragma unroll
    for (int mt = 0; mt < 4; ++mt) {
      hv[0][mt] = h[(size_t)(bn0 + mt) * CC + col0];
      hv[1][mt] = h[(size_t)(bn0 + mt) * CC + col1];
    }
  }
  bf16x8 Ba[2][4];
  #pragma unroll
  for (int t2 = 0; t2 < 2; ++t2) {
    int row = w * 32 + t2 * 16 + l15;
    #pragma unroll
    for (int s = 0; s < 4; ++s)
      Ba[t2][s] = cvt8(Wa + (size_t)row * CC + s * 32 + quad * 8);
  }

  // logits = u @ Wa^T
  f32x4 accl[2][4] = {};
  #pragma unroll
  for (int s = 0; s < 4; ++s) {
    bf16x8 af[4];
    #pragma unroll
    for (int mt = 0; mt < 4; ++mt)
      af[mt] = *(const bf16x8*)(&ts[(mt * 16 + l15) * 136 + s * 32 + quad * 8]);
    #pragma unroll
    for (int t2 = 0; t2 < 2; ++t2)
      #pragma unroll
      for (int mt = 0; mt < 4; ++mt)
        accl[t2][mt] = MFMA16(af[mt], Ba[t2][s], accl[t2][mt]);
  }

  // softmax over j (rows within each point/mt), y, residual
  #pragma unroll
  for (int t2 = 0; t2 < 2; ++t2) {
    int col = t2 ? col1 : col0;
    float bav = ba[col];
    #pragma unroll
    for (int mt = 0; mt < 4; ++mt) {
      float lv0 = accl[t2][mt][0] + bav, lv1 = accl[t2][mt][1] + bav;
      float lv2 = accl[t2][mt][2] + bav, lv3 = accl[t2][mt][3] + bav;
      float mx = fmaxf(fmaxf(lv0, lv1), fmaxf(lv2, lv3));
      mx = fmaxf(mx, __shfl_xor(mx, 16));
      mx = fmaxf(mx, __shfl_xor(mx, 32));
      float e0 = __expf(lv0 - mx), e1 = __expf(lv1 - mx);
      float e2 = __expf(lv2 - mx), e3 = __expf(lv3 - mx);
      float ss = e0 + e1 + e2 + e3;
      ss += __shfl_xor(ss, 16); ss += __shfl_xor(ss, 32);
      float yv = e0 * (vreg[t2][mt][0] + accd[t2][mt][0])
               + e1 * (vreg[t2][mt][1] + accd[t2][mt][1])
               + e2 * (vreg[t2][mt][2] + accd[t2][mt][2])
               + e3 * (vreg[t2][mt][3] + accd[t2][mt][3]);
      yv += __shfl_xor(yv, 16); yv += __shfl_xor(yv, 32);
      if (quad == 0) {
        float hvv = hv[t2][mt] + yv / ss;
        hres[(size_t)(bn0 + mt) * CC + col] = hvv;
        hrs[mt * 128 + col] = hvv;
      }
    }
  }
  __syncthreads();

  // fused LN2: wave w normalizes point w, writes h2 bf16
  {
    int c0 = lane * 2;
    float v0 = hrs[w * 128 + c0], v1 = hrs[w * 128 + c0 + 1];
    float s1 = v0 + v1, s2 = v0 * v0 + v1 * v1;
    #pragma unroll
    for (int off = 1; off < 64; off <<= 1) { s1 += __shfl_xor(s1, off); s2 += __shfl_xor(s2, off); }
    float mu = s1 * (1.f / CC);
    float var = s2 * (1.f / CC) - mu * mu;
    float rs = rsqrtf(var + 1e-5f);
    bf16x2 o;
    o[0] = (__bf16)((v0 - mu) * rs * g2[c0] + b2[c0]);
    o[1] = (__bf16)((v1 - mu) * rs * g2[c0 + 1] + b2[c0 + 1]);
    *(bf16x2*)(h2 + (size_t)(bn0 + w) * CC + c0) = o;
  }
}

// ============================================================
extern "C" void kernel_launch(void* const* d_in, const int* in_sizes, int n_in,
                              void* d_out, int out_size, void* d_ws, size_t ws_size,
                              hipStream_t stream) {
  const float* x   = (const float*)d_in[0];
  const float* p   = (const float*)d_in[1];
  const float* Win = (const float*)d_in[2];
  const float* bin = (const float*)d_in[3];
  const float* Wq  = (const float*)d_in[4];
  const float* Wk  = (const float*)d_in[5];
  const float* Wv  = (const float*)d_in[6];
  const float* Wd1 = (const float*)d_in[7];
  const float* bd1 = (const float*)d_in[8];
  const float* Wd2 = (const float*)d_in[9];
  const float* bd2 = (const float*)d_in[10];
  const float* Wa  = (const float*)d_in[11];
  const float* ba  = (const float*)d_in[12];
  const float* g1  = (const float*)d_in[13];
  const float* b1  = (const float*)d_in[14];
  const float* g2  = (const float*)d_in[15];
  const float* b2  = (const float*)d_in[16];
  const float* Wf1 = (const float*)d_in[17];
  const float* bf1 = (const float*)d_in[18];
  const float* Wf2 = (const float*)d_in[19];
  const float* bf2 = (const float*)d_in[20];
  float* out = (float*)d_out;

  const size_t SZ = (size_t)BNT * CC;   // 2,097,152
  float* wsf = (float*)d_ws;
  float*  h    = wsf;
  bf16_t* hnb  = (bf16_t*)(wsf + SZ);
  float*  hres = wsf + SZ;
  float*  q    = wsf + 2 * SZ;
  bf16_t* kb   = (bf16_t*)(wsf + 3 * SZ);
  bf16_t* vb   = kb + SZ;
  bf16_t* g    = (bf16_t*)(wsf + 2 * SZ);
  bf16_t* h2   = (bf16_t*)(wsf + 4 * SZ);
  int*    idxw = (int*)(wsf + 4 * SZ + SZ / 2);

  inproj_ln_k<<<BNT / 64, 256, 0, stream>>>(x, Win, bin, g1, b1, h, hnb);
  knn_k<<<BB * (NN / 4), 256, 0, stream>>>(p, idxw);
  gemm_qkv_k<<<dim3(BNT / 64, 6), 256, 0, stream>>>(hnb, Wq, Wk, Wv, q, kb, vb);
  attn_k<<<BNT / 4, 256, 0, stream>>>(q, kb, vb, p, idxw, Wd1, bd1, Wd2, bd2, Wa, ba,
                                      g2, b2, h, hres, h2);
  gemm_k<1><<<dim3(BNT / 64, 8), 256, 0, stream>>>(h2, Wf1, bf1, nullptr, g, nullptr, 4 * CC, CC);
  gemm_k<2><<<dim3(BNT / 64, 2), 256, 0, stream>>>(g, Wf2, bf2, out, nullptr, hres, CC, 4 * CC);
}